// Round 3
// baseline (784.826 us; speedup 1.0000x reference)
//
#include <hip/hip_runtime.h>
#include <math.h>

#define NQ 100000
#define NL 32
#define QD 384
#define LD 1024
#define H 128
#define E_TOT 1000000
#define E_SEE 750000
#define E_PRED 250000
#define NN (NQ + NL)          // 100032
#define EPS 1e-5f

#define NB_SCAN ((NN + 255) / 256)    // 391
#define NB_GEMM ((NN + 127) / 128)    // 782
#define NB_XINI ((NQ + 63) / 64)      // 1563  (64 rows/block, 16 rows/wave)

typedef __attribute__((ext_vector_type(8))) short short8;
typedef __attribute__((ext_vector_type(4))) short short4v;
typedef __attribute__((ext_vector_type(4))) float f32x4;
typedef __attribute__((ext_vector_type(4))) unsigned int uint4v;

__device__ __forceinline__ unsigned short f2bf(float f) {
  unsigned int u = __builtin_bit_cast(unsigned int, f);
  u = (u + 0x7FFFu + ((u >> 16) & 1u)) >> 16;
  return (unsigned short)u;
}

// ---------------- CSR build ----------------

__global__ void k_ew_hist(const int* __restrict__ ecs, const int* __restrict__ EI,
                          const float* __restrict__ ewt, const float* __restrict__ Wem,
                          const float* __restrict__ bem, float* __restrict__ ew,
                          int* __restrict__ cnt) {
  int e = blockIdx.x * 256 + threadIdx.x;
  if (e >= E_SEE) return;
  int idx = ecs[e];
  int d = EI[E_TOT + idx];
  atomicAdd(&cnt[d], 1);
  float w = ewt[idx] * Wem[0] + bem[0];
  ew[e] = w > 0.f ? w : 0.01f * w;
}

__global__ void k_scan_block(const int* __restrict__ cnt, int* __restrict__ bsum) {
  __shared__ int red[256];
  int i = blockIdx.x * 256 + threadIdx.x;
  red[threadIdx.x] = (i < NN) ? cnt[i] : 0;
  __syncthreads();
  for (int s = 128; s > 0; s >>= 1) {
    if (threadIdx.x < s) red[threadIdx.x] += red[threadIdx.x + s];
    __syncthreads();
  }
  if (threadIdx.x == 0) bsum[blockIdx.x] = red[0];
}

__global__ void k_scan_top(const int* __restrict__ bsum, int* __restrict__ boff) {
  __shared__ int buf[2][512];
  int t = threadIdx.x;
  int v = (t < NB_SCAN) ? bsum[t] : 0;
  buf[0][t] = v;
  __syncthreads();
  int src = 0;
  for (int d = 1; d < 512; d <<= 1) {
    int x = buf[src][t];
    if (t >= d) x += buf[src][t - d];
    buf[src ^ 1][t] = x;
    __syncthreads();
    src ^= 1;
  }
  if (t < NB_SCAN) boff[t] = buf[src][t] - v;  // exclusive
}

__global__ void k_scan_write(const int* __restrict__ cnt, const int* __restrict__ boff,
                             int* __restrict__ off) {
  __shared__ int buf[2][256];
  int t = threadIdx.x;
  int i = blockIdx.x * 256 + t;
  int v = (i < NN) ? cnt[i] : 0;
  buf[0][t] = v;
  __syncthreads();
  int src = 0;
  for (int d = 1; d < 256; d <<= 1) {
    int x = buf[src][t];
    if (t >= d) x += buf[src][t - d];
    buf[src ^ 1][t] = x;
    __syncthreads();
    src ^= 1;
  }
  if (i < NN) off[i] = boff[blockIdx.x] + buf[src][t] - v;
  if (i == 0) off[NN] = E_SEE;
}

__global__ void k_fill(const int* __restrict__ ecs, const int* __restrict__ EI,
                       const float* __restrict__ ew, const int* __restrict__ off,
                       int* __restrict__ cur, int* __restrict__ csr_src,
                       float* __restrict__ csr_ew) {
  int e = blockIdx.x * 256 + threadIdx.x;
  if (e >= E_SEE) return;
  int idx = ecs[e];
  int s = EI[idx];
  int d = EI[E_TOT + idx];
  int p = off[d] + atomicAdd(&cur[d], 1);
  csr_src[p] = s;
  csr_ew[p] = ew[e];
}

// ---------------- prep: bf16 transposed weights [n][k] ----------------

__global__ void k_prep(const float* __restrict__ Wq, const float* __restrict__ W1m,
                       const float* __restrict__ W2m,
                       unsigned short* __restrict__ Wqt, unsigned short* __restrict__ W1t,
                       unsigned short* __restrict__ W2t) {
  int i = blockIdx.x * 256 + threadIdx.x;  // grid covers 81920
  const int tot1 = QD * H;                 // 49152
  const int tot2 = H * H;                  // 16384
  if (i < tot1) {
    int n = i / QD, k = i - n * QD;
    Wqt[i] = f2bf(Wq[(size_t)k * H + n]);
  } else if (i < tot1 + tot2) {
    int j = i - tot1;
    int n = j >> 7, k = j & 127;
    W1t[j] = f2bf(W1m[(size_t)k * H + n]);
  } else if (i < tot1 + 2 * tot2) {
    int j = i - tot1 - tot2;
    int n = j >> 7, k = j & 127;
    W2t[j] = f2bf(W2m[(size_t)k * H + n]);
  }
}

// ---------------- llm rows: split-K partial + combine ----------------

__global__ __launch_bounds__(128) void k_llm_part(const float* __restrict__ lf,
                                                  const float* __restrict__ Wl,
                                                  float* __restrict__ part) {
  int r = blockIdx.x >> 3;   // 0..31
  int s = blockIdx.x & 7;    // 0..7
  int t = threadIdx.x;       // col 0..127
  int k0 = s * 128;
  float acc = 0.f;
#pragma unroll 4
  for (int k = 0; k < 128; k += 4) {
    float a0 = lf[(size_t)r * LD + k0 + k + 0];
    float a1 = lf[(size_t)r * LD + k0 + k + 1];
    float a2 = lf[(size_t)r * LD + k0 + k + 2];
    float a3 = lf[(size_t)r * LD + k0 + k + 3];
    acc = fmaf(a0, Wl[(size_t)(k0 + k + 0) * H + t], acc);
    acc = fmaf(a1, Wl[(size_t)(k0 + k + 1) * H + t], acc);
    acc = fmaf(a2, Wl[(size_t)(k0 + k + 2) * H + t], acc);
    acc = fmaf(a3, Wl[(size_t)(k0 + k + 3) * H + t], acc);
  }
  part[(size_t)blockIdx.x * 128 + t] = acc;
}

__global__ void k_llm_comb(const float* __restrict__ part, const float* __restrict__ bl,
                           float* __restrict__ XINI) {
  int i = blockIdx.x * 256 + threadIdx.x;
  if (i >= NL * H) return;
  int r = i >> 7, t = i & 127;
  float a = bl[t];
#pragma unroll
  for (int s = 0; s < 8; s++) a += part[(size_t)(r * 8 + s) * 128 + t];
  XINI[(size_t)(NQ + r) * H + t] = a;
}

// ---------------- x_ini q rows: wave-autonomous bf16 MFMA, no LDS, no barriers ----
// 16 rows x 128 cols per wave (small tile => 2x wave count => TLP hides HBM
// latency), A prefetched depth-2 in NAMED float4 regs (slot0/slot1 hand-unrolled,
// no arrays => no spill; verify via WRITE_SIZE == ~50 MB). B fragments are
// direct int4 loads from bf16 Wqt (96 KB, L2-resident).

__global__ __launch_bounds__(256, 4) void k_xini(
    const float* __restrict__ qf, const unsigned short* __restrict__ Wqt,
    const float* __restrict__ bq, float* __restrict__ XINI) {
  int tid = threadIdx.x;
  int lane = tid & 63;
  int w = tid >> 6;
  int l15 = lane & 15, quad = lane >> 4;
  int rowbase = blockIdx.x * 64 + w * 16;

  f32x4 acc[8];
#pragma unroll
  for (int j = 0; j < 8; ++j) acc[j] = (f32x4){0.f, 0.f, 0.f, 0.f};

  int r0 = rowbase + l15;
  const float* rp0 = qf + (size_t)r0 * QD + quad * 8;
  bool v0 = r0 < NQ;
  const unsigned short* bp = Wqt + (size_t)l15 * QD + quad * 8;

  const float4 z4 = make_float4(0.f, 0.f, 0.f, 0.f);
  // depth-2 A prefetch, named regs (slot0: s0a/s0b, slot1: s1a/s1b)
  float4 s0a = v0 ? *(const float4*)(rp0 + 0) : z4;
  float4 s0b = v0 ? *(const float4*)(rp0 + 4) : z4;
  float4 s1a = v0 ? *(const float4*)(rp0 + 32) : z4;
  float4 s1b = v0 ? *(const float4*)(rp0 + 36) : z4;

#define XSTEP(KB, SA, SB)                                                      \
  do {                                                                         \
    short8 bfr[8];                                                             \
    _Pragma("unroll")                                                          \
    for (int nt = 0; nt < 8; ++nt)                                             \
      bfr[nt] = *(const short8*)(bp + (size_t)nt * 16 * QD + (KB));            \
    uint4v pk;                                                                 \
    pk.x = ((unsigned int)f2bf(SA.y) << 16) | f2bf(SA.x);                      \
    pk.y = ((unsigned int)f2bf(SA.w) << 16) | f2bf(SA.z);                      \
    pk.z = ((unsigned int)f2bf(SB.y) << 16) | f2bf(SB.x);                      \
    pk.w = ((unsigned int)f2bf(SB.w) << 16) | f2bf(SB.z);                      \
    short8 af = __builtin_bit_cast(short8, pk);                                \
    if ((KB) + 64 < 384) { /* reissue this slot for step+2 */                  \
      SA = v0 ? *(const float4*)(rp0 + (KB) + 64) : z4;                        \
      SB = v0 ? *(const float4*)(rp0 + (KB) + 68) : z4;                        \
    }                                                                          \
    _Pragma("unroll")                                                          \
    for (int nt = 0; nt < 8; ++nt)                                             \
      acc[nt] = __builtin_amdgcn_mfma_f32_16x16x32_bf16(af, bfr[nt],           \
                                                        acc[nt], 0, 0, 0);     \
  } while (0)

  for (int kb = 0; kb < 384; kb += 64) {
    XSTEP(kb, s0a, s0b);
    XSTEP(kb + 32, s1a, s1b);
  }
#undef XSTEP

  float bias[8];
#pragma unroll
  for (int nt = 0; nt < 8; ++nt) bias[nt] = bq[nt * 16 + l15];
#pragma unroll
  for (int r = 0; r < 4; ++r) {
    int n = rowbase + quad * 4 + r;
    if (n < NQ) {
#pragma unroll
      for (int nt = 0; nt < 8; ++nt)
        XINI[(size_t)n * H + nt * 16 + l15] = acc[nt][r] + bias[nt];
    }
  }
}

// ---------------- segment sum (one wave per node), S stored bf16 ----------------

template <bool TRANS>
__global__ __launch_bounds__(256) void k_seg(
    const float* __restrict__ Xin, const int* __restrict__ off,
    const int* __restrict__ csr_src, const float* __restrict__ csr_ew,
    const float* __restrict__ scale, const float* __restrict__ shift,
    unsigned short* __restrict__ S16, float* __restrict__ swsum,
    float* __restrict__ degf) {
  int w = blockIdx.x * 4 + (threadIdx.x >> 6);
  if (w >= NN) return;
  int lane = threadIdx.x & 63;
  int o0 = off[w], o1 = off[w + 1];
  float ax = 1.f, ay = 1.f, bx = 0.f, by = 0.f;
  if (TRANS) {
    float2 sc = *(const float2*)&scale[lane * 2];
    float2 sh = *(const float2*)&shift[lane * 2];
    ax = sc.x; ay = sc.y; bx = sh.x; by = sh.y;
  }
  float accx = 0.f, accy = 0.f, ews = 0.f;
  for (int k = o0; k < o1; ++k) {
    int s = csr_src[k];
    float2 v = *(const float2*)&Xin[(size_t)s * H + lane * 2];
    if (TRANS) {
      float t0 = fmaf(ax, v.x, bx); v.x = t0 > 0.f ? t0 : 0.01f * t0;
      float t1 = fmaf(ay, v.y, by); v.y = t1 > 0.f ? t1 : 0.01f * t1;
    }
    accx += v.x; accy += v.y;
    ews += csr_ew[k];
  }
  unsigned int pk = ((unsigned int)f2bf(accy) << 16) | f2bf(accx);
  *(unsigned int*)&S16[(size_t)w * H + lane * 2] = pk;
  if (lane == 0) { swsum[w] = ews; degf[w] = (float)(o1 - o0); }
}

// ---------------- node GEMM (bf16 MFMA) + residual + BN partials ----------------
// out = S@W + deg*(bm+be) + swsum*We + resid(in); resid: TRANS ? lrelu(a*in+b) : in

template <bool TRANS>
__global__ __launch_bounds__(256) void k_gemm(
    const unsigned short* __restrict__ S16, const float* __restrict__ Xin,
    float* __restrict__ Xout, const unsigned short* __restrict__ Wt,
    const float* __restrict__ bm, const float* __restrict__ be,
    const float* __restrict__ We,
    const float* __restrict__ scale, const float* __restrict__ shift,
    const float* __restrict__ swsum, const float* __restrict__ degf,
    float* __restrict__ partials) {
  __shared__ unsigned short sA[128][40];
  __shared__ unsigned short sB[128][40];
  __shared__ float st[2][8][128];
  int tid = threadIdx.x;
  int w = tid >> 6, lane = tid & 63;
  int l15 = lane & 15, quad = lane >> 4;
  int wr = (w >> 1) * 64, wc = (w & 1) * 64;
  int rowbase = blockIdx.x * 128;
  f32x4 acc[4][4];
#pragma unroll
  for (int i = 0; i < 4; i++)
#pragma unroll
    for (int j = 0; j < 4; j++) acc[i][j] = (f32x4){0.f, 0.f, 0.f, 0.f};

  int arow = tid >> 1, ah = (tid & 1) * 16;  // 128 rows x 32 k per step
  int4 pa[2], pb[2];
  {
    int gr = rowbase + arow;
    if (gr < NN) {
      pa[0] = *(const int4*)&S16[(size_t)gr * H + ah];
      pa[1] = *(const int4*)&S16[(size_t)gr * H + ah + 8];
    } else {
      pa[0] = make_int4(0, 0, 0, 0); pa[1] = make_int4(0, 0, 0, 0);
    }
    pb[0] = *(const int4*)&Wt[(size_t)arow * H + ah];
    pb[1] = *(const int4*)&Wt[(size_t)arow * H + ah + 8];
  }
  for (int step = 0; step < 4; ++step) {
    *(int4*)&sA[arow][ah] = pa[0];
    *(int4*)&sA[arow][ah + 8] = pa[1];
    *(int4*)&sB[arow][ah] = pb[0];
    *(int4*)&sB[arow][ah + 8] = pb[1];
    __syncthreads();
    if (step + 1 < 4) {
      int kn = (step + 1) * 32;
      int gr = rowbase + arow;
      if (gr < NN) {
        pa[0] = *(const int4*)&S16[(size_t)gr * H + kn + ah];
        pa[1] = *(const int4*)&S16[(size_t)gr * H + kn + ah + 8];
      } else {
        pa[0] = make_int4(0, 0, 0, 0); pa[1] = make_int4(0, 0, 0, 0);
      }
      pb[0] = *(const int4*)&Wt[(size_t)arow * H + kn + ah];
      pb[1] = *(const int4*)&Wt[(size_t)arow * H + kn + ah + 8];
    }
    short8 af[4], bfr[4];
#pragma unroll
    for (int mt = 0; mt < 4; ++mt)
      af[mt] = *(const short8*)&sA[wr + mt * 16 + l15][quad * 8];
#pragma unroll
    for (int nt = 0; nt < 4; ++nt)
      bfr[nt] = *(const short8*)&sB[wc + nt * 16 + l15][quad * 8];
#pragma unroll
    for (int mt = 0; mt < 4; ++mt)
#pragma unroll
      for (int nt = 0; nt < 4; ++nt)
        acc[mt][nt] = __builtin_amdgcn_mfma_f32_16x16x32_bf16(
            af[mt], bfr[nt], acc[mt][nt], 0, 0, 0);
    __syncthreads();
  }
  // epilogue
  int col4[4];
  float cb4[4], we4[4], sc4[4], sh4[4], ps[4], pq[4];
#pragma unroll
  for (int nt = 0; nt < 4; ++nt) {
    int col = wc + nt * 16 + l15;
    col4[nt] = col;
    cb4[nt] = bm[col] + be[col];
    we4[nt] = We[col];
    if (TRANS) { sc4[nt] = scale[col]; sh4[nt] = shift[col]; }
    ps[nt] = 0.f; pq[nt] = 0.f;
  }
#pragma unroll
  for (int mt = 0; mt < 4; ++mt) {
#pragma unroll
    for (int r = 0; r < 4; ++r) {
      int n = rowbase + wr + mt * 16 + quad * 4 + r;
      if (n < NN) {
        float dg = degf[n], sw = swsum[n];
#pragma unroll
        for (int nt = 0; nt < 4; ++nt) {
          float rr = Xin[(size_t)n * H + col4[nt]];
          if (TRANS) {
            float t = fmaf(sc4[nt], rr, sh4[nt]);
            rr = t > 0.f ? t : 0.01f * t;
          }
          float o = acc[mt][nt][r] + dg * cb4[nt] + sw * we4[nt] + rr;
          Xout[(size_t)n * H + col4[nt]] = o;
          ps[nt] += o; pq[nt] += o * o;
        }
      }
    }
  }
  int slot = (w >> 1) * 4 + quad;
#pragma unroll
  for (int nt = 0; nt < 4; ++nt) {
    st[0][slot][col4[nt]] = ps[nt];
    st[1][slot][col4[nt]] = pq[nt];
  }
  __syncthreads();
  int plane = tid >> 7, col = tid & 127;
  float s = 0.f;
#pragma unroll
  for (int y = 0; y < 8; y++) s += st[plane][y][col];
  partials[(size_t)blockIdx.x * 256 + tid] = s;
}

// ---------------- BN stats finish: one block per column ----------------

__global__ __launch_bounds__(256) void k_bnstats(
    const float* __restrict__ partials, const float* __restrict__ g,
    const float* __restrict__ beta, float* __restrict__ scale,
    float* __restrict__ shift) {
  __shared__ float rs[256], rq[256];
  int j = blockIdx.x;  // column
  int t = threadIdx.x;
  float as = 0.f, aq = 0.f;
  for (int b = t; b < NB_GEMM; b += 256) {
    as += partials[(size_t)b * 256 + j];
    aq += partials[(size_t)b * 256 + 128 + j];
  }
  rs[t] = as; rq[t] = aq;
  __syncthreads();
  for (int s = 128; s > 0; s >>= 1) {
    if (t < s) { rs[t] += rs[t + s]; rq[t] += rq[t + s]; }
    __syncthreads();
  }
  if (t == 0) {
    float mean = rs[0] / (float)NN;
    float var = rq[0] / (float)NN - mean * mean;
    float a = g[j] * rsqrtf(var + EPS);
    scale[j] = a;
    shift[j] = beta[j] - mean * a;
  }
}

// ---------------- edge predict (one wave per edge) ----------------

__global__ __launch_bounds__(256) void k_pred(
    const int* __restrict__ emask, const int* __restrict__ EI,
    const float* __restrict__ XINI, const float* __restrict__ X,
    const float* __restrict__ scale, const float* __restrict__ shift,
    float* __restrict__ out) {
  int i = blockIdx.x * 4 + (threadIdx.x >> 6);
  if (i >= E_PRED) return;
  int lane = threadIdx.x & 63;
  int m = emask[i];
  int p0 = EI[m];
  int p1 = EI[E_TOT + m];
  float2 a = *(const float2*)&XINI[(size_t)p0 * H + lane * 2];
  float2 b = *(const float2*)&X[(size_t)p1 * H + lane * 2];
  float2 sc = *(const float2*)&scale[lane * 2];
  float2 sh = *(const float2*)&shift[lane * 2];
  float v = a.x * fmaf(sc.x, b.x, sh.x) + a.y * fmaf(sc.y, b.y, sh.y);
#pragma unroll
  for (int mm = 32; mm > 0; mm >>= 1) v += __shfl_xor(v, mm, 64);
  if (lane == 0) out[i] = 1.f / (1.f + expf(-v * (1.f / 128.f)));
}

// ---------------- launcher ----------------

extern "C" void kernel_launch(void* const* d_in, const int* in_sizes, int n_in,
                              void* d_out, int out_size, void* d_ws, size_t ws_size,
                              hipStream_t stream) {
  const float* qf    = (const float*)d_in[0];
  const float* lf    = (const float*)d_in[1];
  const int*   EI    = (const int*)d_in[2];
  const int*   emask = (const int*)d_in[3];
  const int*   ecs   = (const int*)d_in[4];
  const float* ewt   = (const float*)d_in[5];
  const float* Wq    = (const float*)d_in[6];
  const float* bq    = (const float*)d_in[7];
  const float* Wl    = (const float*)d_in[8];
  const float* bl    = (const float*)d_in[9];
  const float* Wem   = (const float*)d_in[10];
  const float* bem   = (const float*)d_in[11];
  const float* W1m   = (const float*)d_in[12];
  const float* b1m   = (const float*)d_in[13];
  const float* W1e   = (const float*)d_in[14];
  const float* b1e   = (const float*)d_in[15];
  const float* W2m   = (const float*)d_in[16];
  const float* b2m   = (const float*)d_in[17];
  const float* W2e   = (const float*)d_in[18];
  const float* b2e   = (const float*)d_in[19];
  const float* g1    = (const float*)d_in[20];
  const float* beta1 = (const float*)d_in[21];
  const float* g2    = (const float*)d_in[22];
  const float* beta2 = (const float*)d_in[23];
  float* out = (float*)d_out;

  char* p = (char*)d_ws;
  auto alloc = [&](size_t bytes) -> void* {
    void* r = (void*)p;
    p += (bytes + 255) & ~(size_t)255;
    return r;
  };
  float* XINI    = (float*)alloc((size_t)NN * H * 4);
  float* X       = (float*)alloc((size_t)NN * H * 4);
  unsigned short* S16 = (unsigned short*)alloc((size_t)NN * H * 2);
  float* ew      = (float*)alloc((size_t)E_SEE * 4);
  float* csr_ew  = (float*)alloc((size_t)E_SEE * 4);
  int*   csr_src = (int*)alloc((size_t)E_SEE * 4);
  int*   cnt     = (int*)alloc((size_t)NN * 4);
  int*   off     = (int*)alloc((size_t)(NN + 1) * 4);
  int*   cur     = (int*)alloc((size_t)NN * 4);
  int*   bsum    = (int*)alloc((size_t)NB_SCAN * 4);
  int*   boff    = (int*)alloc((size_t)NB_SCAN * 4);
  float* swsum   = (float*)alloc((size_t)NN * 4);
  float* degf    = (float*)alloc((size_t)NN * 4);
  float* partials= (float*)alloc((size_t)NB_GEMM * 256 * 4);
  float* scale1  = (float*)alloc(128 * 4);
  float* shift1  = (float*)alloc(128 * 4);
  float* scale2  = (float*)alloc(128 * 4);
  float* shift2  = (float*)alloc(128 * 4);
  unsigned short* Wqt = (unsigned short*)alloc((size_t)QD * H * 2);
  unsigned short* W1t = (unsigned short*)alloc((size_t)H * H * 2);
  unsigned short* W2t = (unsigned short*)alloc((size_t)H * H * 2);
  float* llmpart = (float*)alloc((size_t)NL * 8 * H * 4);

  hipMemsetAsync(cnt, 0, (size_t)NN * 4, stream);
  hipMemsetAsync(cur, 0, (size_t)NN * 4, stream);

  int ebl = (E_SEE + 255) / 256;
  k_prep<<<320, 256, 0, stream>>>(Wq, W1m, W2m, Wqt, W1t, W2t);
  k_ew_hist<<<ebl, 256, 0, stream>>>(ecs, EI, ewt, Wem, bem, ew, cnt);
  k_scan_block<<<NB_SCAN, 256, 0, stream>>>(cnt, bsum);
  k_scan_top<<<1, 512, 0, stream>>>(bsum, boff);
  k_scan_write<<<NB_SCAN, 256, 0, stream>>>(cnt, boff, off);
  k_fill<<<ebl, 256, 0, stream>>>(ecs, EI, ew, off, cur, csr_src, csr_ew);

  k_llm_part<<<NL * 8, 128, 0, stream>>>(lf, Wl, llmpart);
  k_llm_comb<<<(NL * H + 255) / 256, 256, 0, stream>>>(llmpart, bl, XINI);
  k_xini<<<NB_XINI, 256, 0, stream>>>(qf, Wqt, bq, XINI);

  int segbl = (NN + 3) / 4;
  // layer 1
  k_seg<false><<<segbl, 256, 0, stream>>>(XINI, off, csr_src, csr_ew,
                                          nullptr, nullptr, S16, swsum, degf);
  k_gemm<false><<<NB_GEMM, 256, 0, stream>>>(S16, XINI, X, W1t, b1m, b1e, W1e,
                                             nullptr, nullptr, swsum, degf, partials);
  k_bnstats<<<H, 256, 0, stream>>>(partials, g1, beta1, scale1, shift1);
  // layer 2 (BN1+lrelu folded into gather & residual)
  k_seg<true><<<segbl, 256, 0, stream>>>(X, off, csr_src, csr_ew,
                                         scale1, shift1, S16, swsum, degf);
  k_gemm<true><<<NB_GEMM, 256, 0, stream>>>(S16, X, X, W2t, b2m, b2e, W2e,
                                            scale1, shift1, swsum, degf, partials);
  k_bnstats<<<H, 256, 0, stream>>>(partials, g2, beta2, scale2, shift2);
  // predict (BN2 folded in)
  int pbl = (E_PRED + 3) / 4;
  k_pred<<<pbl, 256, 0, stream>>>(emask, EI, XINI, X, scale2, shift2, out);
}

// Round 4
// 770.948 us; speedup vs baseline: 1.0180x; 1.0180x over previous
//
#include <hip/hip_runtime.h>
#include <math.h>

#define NQ 100000
#define NL 32
#define QD 384
#define LD 1024
#define H 128
#define E_TOT 1000000
#define E_SEE 750000
#define E_PRED 250000
#define NN (NQ + NL)          // 100032
#define EPS 1e-5f

#define NB_SCAN ((NN + 255) / 256)    // 391
#define NB_GEMM ((NN + 127) / 128)    // 782
#define NB_XINI ((NQ + 127) / 128)    // 782  (128 rows/block, 32 rows/wave)

typedef __attribute__((ext_vector_type(8))) short short8;
typedef __attribute__((ext_vector_type(4))) short short4v;
typedef __attribute__((ext_vector_type(4))) float f32x4;
typedef __attribute__((ext_vector_type(4))) unsigned int uint4v;

__device__ __forceinline__ unsigned short f2bf(float f) {
  unsigned int u = __builtin_bit_cast(unsigned int, f);
  u = (u + 0x7FFFu + ((u >> 16) & 1u)) >> 16;
  return (unsigned short)u;
}

// ---------------- CSR build ----------------

__global__ void k_ew_hist(const int* __restrict__ ecs, const int* __restrict__ EI,
                          const float* __restrict__ ewt, const float* __restrict__ Wem,
                          const float* __restrict__ bem, float* __restrict__ ew,
                          int* __restrict__ cnt) {
  int e = blockIdx.x * 256 + threadIdx.x;
  if (e >= E_SEE) return;
  int idx = ecs[e];
  int d = EI[E_TOT + idx];
  atomicAdd(&cnt[d], 1);
  float w = ewt[idx] * Wem[0] + bem[0];
  ew[e] = w > 0.f ? w : 0.01f * w;
}

__global__ void k_scan_block(const int* __restrict__ cnt, int* __restrict__ bsum) {
  __shared__ int red[256];
  int i = blockIdx.x * 256 + threadIdx.x;
  red[threadIdx.x] = (i < NN) ? cnt[i] : 0;
  __syncthreads();
  for (int s = 128; s > 0; s >>= 1) {
    if (threadIdx.x < s) red[threadIdx.x] += red[threadIdx.x + s];
    __syncthreads();
  }
  if (threadIdx.x == 0) bsum[blockIdx.x] = red[0];
}

__global__ void k_scan_top(const int* __restrict__ bsum, int* __restrict__ boff) {
  __shared__ int buf[2][512];
  int t = threadIdx.x;
  int v = (t < NB_SCAN) ? bsum[t] : 0;
  buf[0][t] = v;
  __syncthreads();
  int src = 0;
  for (int d = 1; d < 512; d <<= 1) {
    int x = buf[src][t];
    if (t >= d) x += buf[src][t - d];
    buf[src ^ 1][t] = x;
    __syncthreads();
    src ^= 1;
  }
  if (t < NB_SCAN) boff[t] = buf[src][t] - v;  // exclusive
}

__global__ void k_scan_write(const int* __restrict__ cnt, const int* __restrict__ boff,
                             int* __restrict__ off) {
  __shared__ int buf[2][256];
  int t = threadIdx.x;
  int i = blockIdx.x * 256 + t;
  int v = (i < NN) ? cnt[i] : 0;
  buf[0][t] = v;
  __syncthreads();
  int src = 0;
  for (int d = 1; d < 256; d <<= 1) {
    int x = buf[src][t];
    if (t >= d) x += buf[src][t - d];
    buf[src ^ 1][t] = x;
    __syncthreads();
    src ^= 1;
  }
  if (i < NN) off[i] = boff[blockIdx.x] + buf[src][t] - v;
  if (i == 0) off[NN] = E_SEE;
}

__global__ void k_fill(const int* __restrict__ ecs, const int* __restrict__ EI,
                       const float* __restrict__ ew, const int* __restrict__ off,
                       int* __restrict__ cur, int* __restrict__ csr_src,
                       float* __restrict__ csr_ew) {
  int e = blockIdx.x * 256 + threadIdx.x;
  if (e >= E_SEE) return;
  int idx = ecs[e];
  int s = EI[idx];
  int d = EI[E_TOT + idx];
  int p = off[d] + atomicAdd(&cur[d], 1);
  csr_src[p] = s;
  csr_ew[p] = ew[e];
}

// ---------------- prep: bf16 transposed weights [n][k] ----------------

__global__ void k_prep(const float* __restrict__ Wq, const float* __restrict__ W1m,
                       const float* __restrict__ W2m,
                       unsigned short* __restrict__ Wqt, unsigned short* __restrict__ W1t,
                       unsigned short* __restrict__ W2t) {
  int i = blockIdx.x * 256 + threadIdx.x;  // grid covers 81920
  const int tot1 = QD * H;                 // 49152
  const int tot2 = H * H;                  // 16384
  if (i < tot1) {
    int n = i / QD, k = i - n * QD;
    Wqt[i] = f2bf(Wq[(size_t)k * H + n]);
  } else if (i < tot1 + tot2) {
    int j = i - tot1;
    int n = j >> 7, k = j & 127;
    W1t[j] = f2bf(W1m[(size_t)k * H + n]);
  } else if (i < tot1 + 2 * tot2) {
    int j = i - tot1 - tot2;
    int n = j >> 7, k = j & 127;
    W2t[j] = f2bf(W2m[(size_t)k * H + n]);
  }
}

// ---------------- llm rows: split-K partial + combine ----------------

__global__ __launch_bounds__(128) void k_llm_part(const float* __restrict__ lf,
                                                  const float* __restrict__ Wl,
                                                  float* __restrict__ part) {
  int r = blockIdx.x >> 3;   // 0..31
  int s = blockIdx.x & 7;    // 0..7
  int t = threadIdx.x;       // col 0..127
  int k0 = s * 128;
  float acc = 0.f;
#pragma unroll 4
  for (int k = 0; k < 128; k += 4) {
    float a0 = lf[(size_t)r * LD + k0 + k + 0];
    float a1 = lf[(size_t)r * LD + k0 + k + 1];
    float a2 = lf[(size_t)r * LD + k0 + k + 2];
    float a3 = lf[(size_t)r * LD + k0 + k + 3];
    acc = fmaf(a0, Wl[(size_t)(k0 + k + 0) * H + t], acc);
    acc = fmaf(a1, Wl[(size_t)(k0 + k + 1) * H + t], acc);
    acc = fmaf(a2, Wl[(size_t)(k0 + k + 2) * H + t], acc);
    acc = fmaf(a3, Wl[(size_t)(k0 + k + 3) * H + t], acc);
  }
  part[(size_t)blockIdx.x * 128 + t] = acc;
}

__global__ void k_llm_comb(const float* __restrict__ part, const float* __restrict__ bl,
                           float* __restrict__ XINI) {
  int i = blockIdx.x * 256 + threadIdx.x;
  if (i >= NL * H) return;
  int r = i >> 7, t = i & 127;
  float a = bl[t];
#pragma unroll
  for (int s = 0; s < 8; s++) a += part[(size_t)(r * 8 + s) * 128 + t];
  XINI[(size_t)(NQ + r) * H + t] = a;
}

// ---------------- x_ini q rows: A in regs (depth-2 named), B via LDS ------------
// 128 rows/block, 4 waves x 32 rows. B (96 KB total) is read from global ONCE per
// block: per K-step an 8 KB slice is reg-staged into a double-buffered LDS tile
// (issue loads early, ds_write after MFMA, ONE barrier/step). This cuts the
// vector-path B traffic from 300 MB (per-wave L2 re-reads) to 75 MB — r1/r3
// showed a ~4.6 TB/s vector-path ceiling, so bytes are the lever.
// LDS row stride = 40 shorts (80 B): bank base 4*(5r mod 8) is a permutation ->
// uniform (floor) bank load on ds_read_b128, unlike r0's skewed layout.

__global__ __launch_bounds__(256, 3) void k_xini(
    const float* __restrict__ qf, const unsigned short* __restrict__ Wqt,
    const float* __restrict__ bq, float* __restrict__ XINI) {
  __shared__ unsigned short sB[2][128][40];
  int tid = threadIdx.x;
  int lane = tid & 63;
  int w = tid >> 6;
  int l15 = lane & 15, quad = lane >> 4;
  int rowbase = blockIdx.x * 128 + w * 32;

  // B staging: thread t covers Wqt row t>>1, shorts [(t&1)*16 .. +15] of each slice
  int trow = tid >> 1;
  int tk = (tid & 1) * 16;
  const unsigned short* bgp = Wqt + (size_t)trow * QD + tk;

  f32x4 acc[2][8];
#pragma unroll
  for (int i = 0; i < 2; ++i)
#pragma unroll
    for (int j = 0; j < 8; ++j) acc[i][j] = (f32x4){0.f, 0.f, 0.f, 0.f};

  int r0 = rowbase + l15;        // rows for mt=0 fragment
  int r1 = rowbase + 16 + l15;   // rows for mt=1 fragment
  const float* rp0 = qf + (size_t)r0 * QD + quad * 8;
  const float* rp1 = qf + (size_t)r1 * QD + quad * 8;
  bool v0 = r0 < NQ, v1 = r1 < NQ;
  const float4 z4 = make_float4(0.f, 0.f, 0.f, 0.f);

  // prologue: stage B slice 0 into buf 0
  {
    int4 g0 = *(const int4*)(bgp + 0);
    int4 g1 = *(const int4*)(bgp + 8);
    *(int4*)&sB[0][trow][tk] = g0;
    *(int4*)&sB[0][trow][tk + 8] = g1;
  }
  // A depth-2 prefetch, named regs: slot0 = k[0..31], slot1 = k[32..63]
  float4 s0a = v0 ? *(const float4*)(rp0 + 0) : z4;
  float4 s0b = v0 ? *(const float4*)(rp0 + 4) : z4;
  float4 s0c = v1 ? *(const float4*)(rp1 + 0) : z4;
  float4 s0d = v1 ? *(const float4*)(rp1 + 4) : z4;
  float4 s1a = v0 ? *(const float4*)(rp0 + 32) : z4;
  float4 s1b = v0 ? *(const float4*)(rp0 + 36) : z4;
  float4 s1c = v1 ? *(const float4*)(rp1 + 32) : z4;
  float4 s1d = v1 ? *(const float4*)(rp1 + 36) : z4;
  __syncthreads();

#define XSTEP(KB, BUF, RA0, RA1, RB0, RB1)                                     \
  do {                                                                         \
    int4 g0, g1;                                                               \
    bool stage = (KB) + 32 < 384;                                              \
    if (stage) { /* issue next B slice early (T14 split) */                    \
      g0 = *(const int4*)(bgp + (KB) + 32);                                    \
      g1 = *(const int4*)(bgp + (KB) + 40);                                    \
    }                                                                          \
    short8 bfr[8];                                                             \
    _Pragma("unroll")                                                          \
    for (int nt = 0; nt < 8; ++nt)                                             \
      bfr[nt] = *(const short8*)&sB[BUF][nt * 16 + l15][quad * 8];             \
    uint4v pk0, pk1;                                                           \
    pk0.x = ((unsigned int)f2bf(RA0.y) << 16) | f2bf(RA0.x);                   \
    pk0.y = ((unsigned int)f2bf(RA0.w) << 16) | f2bf(RA0.z);                   \
    pk0.z = ((unsigned int)f2bf(RA1.y) << 16) | f2bf(RA1.x);                   \
    pk0.w = ((unsigned int)f2bf(RA1.w) << 16) | f2bf(RA1.z);                   \
    pk1.x = ((unsigned int)f2bf(RB0.y) << 16) | f2bf(RB0.x);                   \
    pk1.y = ((unsigned int)f2bf(RB0.w) << 16) | f2bf(RB0.z);                   \
    pk1.z = ((unsigned int)f2bf(RB1.y) << 16) | f2bf(RB1.x);                   \
    pk1.w = ((unsigned int)f2bf(RB1.w) << 16) | f2bf(RB1.z);                   \
    short8 af0 = __builtin_bit_cast(short8, pk0);                              \
    short8 af1 = __builtin_bit_cast(short8, pk1);                              \
    if ((KB) + 64 < 384) { /* reissue this A slot for step+2 */                \
      RA0 = v0 ? *(const float4*)(rp0 + (KB) + 64) : z4;                       \
      RA1 = v0 ? *(const float4*)(rp0 + (KB) + 68) : z4;                       \
      RB0 = v1 ? *(const float4*)(rp1 + (KB) + 64) : z4;                       \
      RB1 = v1 ? *(const float4*)(rp1 + (KB) + 68) : z4;                       \
    }                                                                          \
    _Pragma("unroll")                                                          \
    for (int nt = 0; nt < 8; ++nt) {                                           \
      acc[0][nt] = __builtin_amdgcn_mfma_f32_16x16x32_bf16(af0, bfr[nt],       \
                                                           acc[0][nt], 0, 0, 0); \
      acc[1][nt] = __builtin_amdgcn_mfma_f32_16x16x32_bf16(af1, bfr[nt],       \
                                                           acc[1][nt], 0, 0, 0); \
    }                                                                          \
    if (stage) { /* write next slice, then the step's single barrier */        \
      *(int4*)&sB[(BUF) ^ 1][trow][tk] = g0;                                   \
      *(int4*)&sB[(BUF) ^ 1][trow][tk + 8] = g1;                               \
      __syncthreads();                                                         \
    }                                                                          \
  } while (0)

  for (int kb = 0; kb < 384; kb += 64) {
    XSTEP(kb, 0, s0a, s0b, s0c, s0d);
    XSTEP(kb + 32, 1, s1a, s1b, s1c, s1d);
  }
#undef XSTEP

  float bias[8];
#pragma unroll
  for (int nt = 0; nt < 8; ++nt) bias[nt] = bq[nt * 16 + l15];
#pragma unroll
  for (int mt = 0; mt < 2; ++mt) {
#pragma unroll
    for (int r = 0; r < 4; ++r) {
      int n = rowbase + mt * 16 + quad * 4 + r;
      if (n < NQ) {
#pragma unroll
        for (int nt = 0; nt < 8; ++nt)
          XINI[(size_t)n * H + nt * 16 + l15] = acc[mt][nt][r] + bias[nt];
      }
    }
  }
}

// ---------------- segment sum (one wave per node), S stored bf16 ----------------

template <bool TRANS>
__global__ __launch_bounds__(256) void k_seg(
    const float* __restrict__ Xin, const int* __restrict__ off,
    const int* __restrict__ csr_src, const float* __restrict__ csr_ew,
    const float* __restrict__ scale, const float* __restrict__ shift,
    unsigned short* __restrict__ S16, float* __restrict__ swsum,
    float* __restrict__ degf) {
  int w = blockIdx.x * 4 + (threadIdx.x >> 6);
  if (w >= NN) return;
  int lane = threadIdx.x & 63;
  int o0 = off[w], o1 = off[w + 1];
  float ax = 1.f, ay = 1.f, bx = 0.f, by = 0.f;
  if (TRANS) {
    float2 sc = *(const float2*)&scale[lane * 2];
    float2 sh = *(const float2*)&shift[lane * 2];
    ax = sc.x; ay = sc.y; bx = sh.x; by = sh.y;
  }
  float accx = 0.f, accy = 0.f, ews = 0.f;
  for (int k = o0; k < o1; ++k) {
    int s = csr_src[k];
    float2 v = *(const float2*)&Xin[(size_t)s * H + lane * 2];
    if (TRANS) {
      float t0 = fmaf(ax, v.x, bx); v.x = t0 > 0.f ? t0 : 0.01f * t0;
      float t1 = fmaf(ay, v.y, by); v.y = t1 > 0.f ? t1 : 0.01f * t1;
    }
    accx += v.x; accy += v.y;
    ews += csr_ew[k];
  }
  unsigned int pk = ((unsigned int)f2bf(accy) << 16) | f2bf(accx);
  *(unsigned int*)&S16[(size_t)w * H + lane * 2] = pk;
  if (lane == 0) { swsum[w] = ews; degf[w] = (float)(o1 - o0); }
}

// ---------------- node GEMM (bf16 MFMA) + residual + BN partials ----------------
// out = S@W + deg*(bm+be) + swsum*We + resid(in); resid: TRANS ? lrelu(a*in+b) : in

template <bool TRANS>
__global__ __launch_bounds__(256) void k_gemm(
    const unsigned short* __restrict__ S16, const float* __restrict__ Xin,
    float* __restrict__ Xout, const unsigned short* __restrict__ Wt,
    const float* __restrict__ bm, const float* __restrict__ be,
    const float* __restrict__ We,
    const float* __restrict__ scale, const float* __restrict__ shift,
    const float* __restrict__ swsum, const float* __restrict__ degf,
    float* __restrict__ partials) {
  __shared__ unsigned short sA[128][40];
  __shared__ unsigned short sB[128][40];
  __shared__ float st[2][8][128];
  int tid = threadIdx.x;
  int w = tid >> 6, lane = tid & 63;
  int l15 = lane & 15, quad = lane >> 4;
  int wr = (w >> 1) * 64, wc = (w & 1) * 64;
  int rowbase = blockIdx.x * 128;
  f32x4 acc[4][4];
#pragma unroll
  for (int i = 0; i < 4; i++)
#pragma unroll
    for (int j = 0; j < 4; j++) acc[i][j] = (f32x4){0.f, 0.f, 0.f, 0.f};

  int arow = tid >> 1, ah = (tid & 1) * 16;  // 128 rows x 32 k per step
  int4 pa[2], pb[2];
  {
    int gr = rowbase + arow;
    if (gr < NN) {
      pa[0] = *(const int4*)&S16[(size_t)gr * H + ah];
      pa[1] = *(const int4*)&S16[(size_t)gr * H + ah + 8];
    } else {
      pa[0] = make_int4(0, 0, 0, 0); pa[1] = make_int4(0, 0, 0, 0);
    }
    pb[0] = *(const int4*)&Wt[(size_t)arow * H + ah];
    pb[1] = *(const int4*)&Wt[(size_t)arow * H + ah + 8];
  }
  for (int step = 0; step < 4; ++step) {
    *(int4*)&sA[arow][ah] = pa[0];
    *(int4*)&sA[arow][ah + 8] = pa[1];
    *(int4*)&sB[arow][ah] = pb[0];
    *(int4*)&sB[arow][ah + 8] = pb[1];
    __syncthreads();
    if (step + 1 < 4) {
      int kn = (step + 1) * 32;
      int gr = rowbase + arow;
      if (gr < NN) {
        pa[0] = *(const int4*)&S16[(size_t)gr * H + kn + ah];
        pa[1] = *(const int4*)&S16[(size_t)gr * H + kn + ah + 8];
      } else {
        pa[0] = make_int4(0, 0, 0, 0); pa[1] = make_int4(0, 0, 0, 0);
      }
      pb[0] = *(const int4*)&Wt[(size_t)arow * H + kn + ah];
      pb[1] = *(const int4*)&Wt[(size_t)arow * H + kn + ah + 8];
    }
    short8 af[4], bfr[4];
#pragma unroll
    for (int mt = 0; mt < 4; ++mt)
      af[mt] = *(const short8*)&sA[wr + mt * 16 + l15][quad * 8];
#pragma unroll
    for (int nt = 0; nt < 4; ++nt)
      bfr[nt] = *(const short8*)&sB[wc + nt * 16 + l15][quad * 8];
#pragma unroll
    for (int mt = 0; mt < 4; ++mt)
#pragma unroll
      for (int nt = 0; nt < 4; ++nt)
        acc[mt][nt] = __builtin_amdgcn_mfma_f32_16x16x32_bf16(
            af[mt], bfr[nt], acc[mt][nt], 0, 0, 0);
    __syncthreads();
  }
  // epilogue
  int col4[4];
  float cb4[4], we4[4], sc4[4], sh4[4], ps[4], pq[4];
#pragma unroll
  for (int nt = 0; nt < 4; ++nt) {
    int col = wc + nt * 16 + l15;
    col4[nt] = col;
    cb4[nt] = bm[col] + be[col];
    we4[nt] = We[col];
    if (TRANS) { sc4[nt] = scale[col]; sh4[nt] = shift[col]; }
    ps[nt] = 0.f; pq[nt] = 0.f;
  }
#pragma unroll
  for (int mt = 0; mt < 4; ++mt) {
#pragma unroll
    for (int r = 0; r < 4; ++r) {
      int n = rowbase + wr + mt * 16 + quad * 4 + r;
      if (n < NN) {
        float dg = degf[n], sw = swsum[n];
#pragma unroll
        for (int nt = 0; nt < 4; ++nt) {
          float rr = Xin[(size_t)n * H + col4[nt]];
          if (TRANS) {
            float t = fmaf(sc4[nt], rr, sh4[nt]);
            rr = t > 0.f ? t : 0.01f * t;
          }
          float o = acc[mt][nt][r] + dg * cb4[nt] + sw * we4[nt] + rr;
          Xout[(size_t)n * H + col4[nt]] = o;
          ps[nt] += o; pq[nt] += o * o;
        }
      }
    }
  }
  int slot = (w >> 1) * 4 + quad;
#pragma unroll
  for (int nt = 0; nt < 4; ++nt) {
    st[0][slot][col4[nt]] = ps[nt];
    st[1][slot][col4[nt]] = pq[nt];
  }
  __syncthreads();
  int plane = tid >> 7, col = tid & 127;
  float s = 0.f;
#pragma unroll
  for (int y = 0; y < 8; y++) s += st[plane][y][col];
  partials[(size_t)blockIdx.x * 256 + tid] = s;
}

// ---------------- BN stats finish: one block per column ----------------

__global__ __launch_bounds__(256) void k_bnstats(
    const float* __restrict__ partials, const float* __restrict__ g,
    const float* __restrict__ beta, float* __restrict__ scale,
    float* __restrict__ shift) {
  __shared__ float rs[256], rq[256];
  int j = blockIdx.x;  // column
  int t = threadIdx.x;
  float as = 0.f, aq = 0.f;
  for (int b = t; b < NB_GEMM; b += 256) {
    as += partials[(size_t)b * 256 + j];
    aq += partials[(size_t)b * 256 + 128 + j];
  }
  rs[t] = as; rq[t] = aq;
  __syncthreads();
  for (int s = 128; s > 0; s >>= 1) {
    if (t < s) { rs[t] += rs[t + s]; rq[t] += rq[t + s]; }
    __syncthreads();
  }
  if (t == 0) {
    float mean = rs[0] / (float)NN;
    float var = rq[0] / (float)NN - mean * mean;
    float a = g[j] * rsqrtf(var + EPS);
    scale[j] = a;
    shift[j] = beta[j] - mean * a;
  }
}

// ---------------- edge predict (one wave per edge) ----------------

__global__ __launch_bounds__(256) void k_pred(
    const int* __restrict__ emask, const int* __restrict__ EI,
    const float* __restrict__ XINI, const float* __restrict__ X,
    const float* __restrict__ scale, const float* __restrict__ shift,
    float* __restrict__ out) {
  int i = blockIdx.x * 4 + (threadIdx.x >> 6);
  if (i >= E_PRED) return;
  int lane = threadIdx.x & 63;
  int m = emask[i];
  int p0 = EI[m];
  int p1 = EI[E_TOT + m];
  float2 a = *(const float2*)&XINI[(size_t)p0 * H + lane * 2];
  float2 b = *(const float2*)&X[(size_t)p1 * H + lane * 2];
  float2 sc = *(const float2*)&scale[lane * 2];
  float2 sh = *(const float2*)&shift[lane * 2];
  float v = a.x * fmaf(sc.x, b.x, sh.x) + a.y * fmaf(sc.y, b.y, sh.y);
#pragma unroll
  for (int mm = 32; mm > 0; mm >>= 1) v += __shfl_xor(v, mm, 64);
  if (lane == 0) out[i] = 1.f / (1.f + expf(-v * (1.f / 128.f)));
}

// ---------------- launcher ----------------

extern "C" void kernel_launch(void* const* d_in, const int* in_sizes, int n_in,
                              void* d_out, int out_size, void* d_ws, size_t ws_size,
                              hipStream_t stream) {
  const float* qf    = (const float*)d_in[0];
  const float* lf    = (const float*)d_in[1];
  const int*   EI    = (const int*)d_in[2];
  const int*   emask = (const int*)d_in[3];
  const int*   ecs   = (const int*)d_in[4];
  const float* ewt   = (const float*)d_in[5];
  const float* Wq    = (const float*)d_in[6];
  const float* bq    = (const float*)d_in[7];
  const float* Wl    = (const float*)d_in[8];
  const float* bl    = (const float*)d_in[9];
  const float* Wem   = (const float*)d_in[10];
  const float* bem   = (const float*)d_in[11];
  const float* W1m   = (const float*)d_in[12];
  const float* b1m   = (const float*)d_in[13];
  const float* W1e   = (const float*)d_in[14];
  const float* b1e   = (const float*)d_in[15];
  const float* W2m   = (const float*)d_in[16];
  const float* b2m   = (const float*)d_in[17];
  const float* W2e   = (const float*)d_in[18];
  const float* b2e   = (const float*)d_in[19];
  const float* g1    = (const float*)d_in[20];
  const float* beta1 = (const float*)d_in[21];
  const float* g2    = (const float*)d_in[22];
  const float* beta2 = (const float*)d_in[23];
  float* out = (float*)d_out;

  char* p = (char*)d_ws;
  auto alloc = [&](size_t bytes) -> void* {
    void* r = (void*)p;
    p += (bytes + 255) & ~(size_t)255;
    return r;
  };
  float* XINI    = (float*)alloc((size_t)NN * H * 4);
  float* X       = (float*)alloc((size_t)NN * H * 4);
  unsigned short* S16 = (unsigned short*)alloc((size_t)NN * H * 2);
  float* ew      = (float*)alloc((size_t)E_SEE * 4);
  float* csr_ew  = (float*)alloc((size_t)E_SEE * 4);
  int*   csr_src = (int*)alloc((size_t)E_SEE * 4);
  int*   cnt     = (int*)alloc((size_t)NN * 4);
  int*   off     = (int*)alloc((size_t)(NN + 1) * 4);
  int*   cur     = (int*)alloc((size_t)NN * 4);
  int*   bsum    = (int*)alloc((size_t)NB_SCAN * 4);
  int*   boff    = (int*)alloc((size_t)NB_SCAN * 4);
  float* swsum   = (float*)alloc((size_t)NN * 4);
  float* degf    = (float*)alloc((size_t)NN * 4);
  float* partials= (float*)alloc((size_t)NB_GEMM * 256 * 4);
  float* scale1  = (float*)alloc(128 * 4);
  float* shift1  = (float*)alloc(128 * 4);
  float* scale2  = (float*)alloc(128 * 4);
  float* shift2  = (float*)alloc(128 * 4);
  unsigned short* Wqt = (unsigned short*)alloc((size_t)QD * H * 2);
  unsigned short* W1t = (unsigned short*)alloc((size_t)H * H * 2);
  unsigned short* W2t = (unsigned short*)alloc((size_t)H * H * 2);
  float* llmpart = (float*)alloc((size_t)NL * 8 * H * 4);

  hipMemsetAsync(cnt, 0, (size_t)NN * 4, stream);
  hipMemsetAsync(cur, 0, (size_t)NN * 4, stream);

  int ebl = (E_SEE + 255) / 256;
  k_prep<<<320, 256, 0, stream>>>(Wq, W1m, W2m, Wqt, W1t, W2t);
  k_ew_hist<<<ebl, 256, 0, stream>>>(ecs, EI, ewt, Wem, bem, ew, cnt);
  k_scan_block<<<NB_SCAN, 256, 0, stream>>>(cnt, bsum);
  k_scan_top<<<1, 512, 0, stream>>>(bsum, boff);
  k_scan_write<<<NB_SCAN, 256, 0, stream>>>(cnt, boff, off);
  k_fill<<<ebl, 256, 0, stream>>>(ecs, EI, ew, off, cur, csr_src, csr_ew);

  k_llm_part<<<NL * 8, 128, 0, stream>>>(lf, Wl, llmpart);
  k_llm_comb<<<(NL * H + 255) / 256, 256, 0, stream>>>(llmpart, bl, XINI);
  k_xini<<<NB_XINI, 256, 0, stream>>>(qf, Wqt, bq, XINI);

  int segbl = (NN + 3) / 4;
  // layer 1
  k_seg<false><<<segbl, 256, 0, stream>>>(XINI, off, csr_src, csr_ew,
                                          nullptr, nullptr, S16, swsum, degf);
  k_gemm<false><<<NB_GEMM, 256, 0, stream>>>(S16, XINI, X, W1t, b1m, b1e, W1e,
                                             nullptr, nullptr, swsum, degf, partials);
  k_bnstats<<<H, 256, 0, stream>>>(partials, g1, beta1, scale1, shift1);
  // layer 2 (BN1+lrelu folded into gather & residual)
  k_seg<true><<<segbl, 256, 0, stream>>>(X, off, csr_src, csr_ew,
                                         scale1, shift1, S16, swsum, degf);
  k_gemm<true><<<NB_GEMM, 256, 0, stream>>>(S16, X, X, W2t, b2m, b2e, W2e,
                                            scale1, shift1, swsum, degf, partials);
  k_bnstats<<<H, 256, 0, stream>>>(partials, g2, beta2, scale2, shift2);
  // predict (BN2 folded in)
  int pbl = (E_PRED + 3) / 4;
  k_pred<<<pbl, 256, 0, stream>>>(emask, EI, XINI, X, scale2, shift2, out);
}

// Round 5
// 760.537 us; speedup vs baseline: 1.0319x; 1.0137x over previous
//
#include <hip/hip_runtime.h>
#include <math.h>

#define NQ 100000
#define NL 32
#define QD 384
#define LD 1024
#define H 128
#define E_TOT 1000000
#define E_SEE 750000
#define E_PRED 250000
#define NN (NQ + NL)          // 100032
#define EPS 1e-5f

#define NB_SCAN ((NN + 255) / 256)    // 391
#define NB_GEMM ((NN + 127) / 128)    // 782
#define NB_XINI ((NQ + 127) / 128)    // 782

typedef __attribute__((ext_vector_type(8))) short short8;
typedef __attribute__((ext_vector_type(4))) short short4v;
typedef __attribute__((ext_vector_type(4))) float f32x4;

__device__ __forceinline__ unsigned short f2bf(float f) {
  unsigned int u = __builtin_bit_cast(unsigned int, f);
  u = (u + 0x7FFFu + ((u >> 16) & 1u)) >> 16;
  return (unsigned short)u;
}

// ---------------- CSR build ----------------

__global__ void k_ew_hist(const int* __restrict__ ecs, const int* __restrict__ EI,
                          const float* __restrict__ ewt, const float* __restrict__ Wem,
                          const float* __restrict__ bem, float* __restrict__ ew,
                          int* __restrict__ cnt) {
  int e = blockIdx.x * 256 + threadIdx.x;
  if (e >= E_SEE) return;
  int idx = ecs[e];
  int d = EI[E_TOT + idx];
  atomicAdd(&cnt[d], 1);
  float w = ewt[idx] * Wem[0] + bem[0];
  ew[e] = w > 0.f ? w : 0.01f * w;
}

__global__ void k_scan_block(const int* __restrict__ cnt, int* __restrict__ bsum) {
  __shared__ int red[256];
  int i = blockIdx.x * 256 + threadIdx.x;
  red[threadIdx.x] = (i < NN) ? cnt[i] : 0;
  __syncthreads();
  for (int s = 128; s > 0; s >>= 1) {
    if (threadIdx.x < s) red[threadIdx.x] += red[threadIdx.x + s];
    __syncthreads();
  }
  if (threadIdx.x == 0) bsum[blockIdx.x] = red[0];
}

__global__ void k_scan_top(const int* __restrict__ bsum, int* __restrict__ boff) {
  __shared__ int buf[2][512];
  int t = threadIdx.x;
  int v = (t < NB_SCAN) ? bsum[t] : 0;
  buf[0][t] = v;
  __syncthreads();
  int src = 0;
  for (int d = 1; d < 512; d <<= 1) {
    int x = buf[src][t];
    if (t >= d) x += buf[src][t - d];
    buf[src ^ 1][t] = x;
    __syncthreads();
    src ^= 1;
  }
  if (t < NB_SCAN) boff[t] = buf[src][t] - v;  // exclusive
}

__global__ void k_scan_write(const int* __restrict__ cnt, const int* __restrict__ boff,
                             int* __restrict__ off) {
  __shared__ int buf[2][256];
  int t = threadIdx.x;
  int i = blockIdx.x * 256 + t;
  int v = (i < NN) ? cnt[i] : 0;
  buf[0][t] = v;
  __syncthreads();
  int src = 0;
  for (int d = 1; d < 256; d <<= 1) {
    int x = buf[src][t];
    if (t >= d) x += buf[src][t - d];
    buf[src ^ 1][t] = x;
    __syncthreads();
    src ^= 1;
  }
  if (i < NN) off[i] = boff[blockIdx.x] + buf[src][t] - v;
  if (i == 0) off[NN] = E_SEE;
}

__global__ void k_fill(const int* __restrict__ ecs, const int* __restrict__ EI,
                       const float* __restrict__ ew, const int* __restrict__ off,
                       int* __restrict__ cur, int* __restrict__ csr_src,
                       float* __restrict__ csr_ew) {
  int e = blockIdx.x * 256 + threadIdx.x;
  if (e >= E_SEE) return;
  int idx = ecs[e];
  int s = EI[idx];
  int d = EI[E_TOT + idx];
  int p = off[d] + atomicAdd(&cur[d], 1);
  csr_src[p] = s;
  csr_ew[p] = ew[e];
}

// ---------------- prep: bf16 transposed weights [n][k] ----------------

__global__ void k_prep(const float* __restrict__ Wq, const float* __restrict__ W1m,
                       const float* __restrict__ W2m,
                       unsigned short* __restrict__ Wqt, unsigned short* __restrict__ W1t,
                       unsigned short* __restrict__ W2t) {
  int i = blockIdx.x * 256 + threadIdx.x;  // grid covers 81920
  const int tot1 = QD * H;                 // 49152
  const int tot2 = H * H;                  // 16384
  if (i < tot1) {
    int n = i / QD, k = i - n * QD;
    Wqt[i] = f2bf(Wq[(size_t)k * H + n]);
  } else if (i < tot1 + tot2) {
    int j = i - tot1;
    int n = j >> 7, k = j & 127;
    W1t[j] = f2bf(W1m[(size_t)k * H + n]);
  } else if (i < tot1 + 2 * tot2) {
    int j = i - tot1 - tot2;
    int n = j >> 7, k = j & 127;
    W2t[j] = f2bf(W2m[(size_t)k * H + n]);
  }
}

// ---------------- llm rows: split-K partial + combine ----------------

__global__ __launch_bounds__(128) void k_llm_part(const float* __restrict__ lf,
                                                  const float* __restrict__ Wl,
                                                  float* __restrict__ part) {
  int r = blockIdx.x >> 3;   // 0..31
  int s = blockIdx.x & 7;    // 0..7
  int t = threadIdx.x;       // col 0..127
  int k0 = s * 128;
  float acc = 0.f;
#pragma unroll 4
  for (int k = 0; k < 128; k += 4) {
    float a0 = lf[(size_t)r * LD + k0 + k + 0];
    float a1 = lf[(size_t)r * LD + k0 + k + 1];
    float a2 = lf[(size_t)r * LD + k0 + k + 2];
    float a3 = lf[(size_t)r * LD + k0 + k + 3];
    acc = fmaf(a0, Wl[(size_t)(k0 + k + 0) * H + t], acc);
    acc = fmaf(a1, Wl[(size_t)(k0 + k + 1) * H + t], acc);
    acc = fmaf(a2, Wl[(size_t)(k0 + k + 2) * H + t], acc);
    acc = fmaf(a3, Wl[(size_t)(k0 + k + 3) * H + t], acc);
  }
  part[(size_t)blockIdx.x * 128 + t] = acc;
}

__global__ void k_llm_comb(const float* __restrict__ part, const float* __restrict__ bl,
                           float* __restrict__ XINI, unsigned short* __restrict__ XI16) {
  int i = blockIdx.x * 256 + threadIdx.x;
  if (i >= NL * H) return;
  int r = i >> 7, t = i & 127;
  float a = bl[t];
#pragma unroll
  for (int s = 0; s < 8; s++) a += part[(size_t)(r * 8 + s) * 128 + t];
  XINI[(size_t)(NQ + r) * H + t] = a;
  XI16[(size_t)(NQ + r) * H + t] = f2bf(a);
}

// ---------------- x_ini q rows: bf16 MFMA 128x128 tile, K=384 ----------------
// (round-0 proven structure: LDS A+B, 107 us; do not re-roll — r1-r4 all lost)

__global__ __launch_bounds__(256) void k_xini(
    const float* __restrict__ qf, const unsigned short* __restrict__ Wqt,
    const float* __restrict__ bq, float* __restrict__ XINI,
    unsigned short* __restrict__ XI16) {
  __shared__ unsigned short sA[128][40];  // pad: 20-dword stride
  __shared__ unsigned short sB[128][40];
  int tid = threadIdx.x;
  int w = tid >> 6, lane = tid & 63;
  int l15 = lane & 15, quad = lane >> 4;
  int wr = (w >> 1) * 64, wc = (w & 1) * 64;
  int rowbase = blockIdx.x * 128;
  f32x4 acc[4][4];
#pragma unroll
  for (int i = 0; i < 4; i++)
#pragma unroll
    for (int j = 0; j < 4; j++) acc[i][j] = (f32x4){0.f, 0.f, 0.f, 0.f};

  int arow = tid >> 3, akc = (tid & 7) * 4;
  int bn = tid >> 2, bk8 = (tid & 3) * 8;
  float4 pa[4];
  int4 pb[2];
  // preload step 0
#pragma unroll
  for (int p = 0; p < 4; ++p) {
    int gr = rowbase + p * 32 + arow;
    pa[p] = (gr < NQ) ? *(const float4*)&qf[(size_t)gr * QD + akc]
                      : make_float4(0.f, 0.f, 0.f, 0.f);
  }
#pragma unroll
  for (int p = 0; p < 2; ++p)
    pb[p] = *(const int4*)&Wqt[(size_t)(p * 64 + bn) * QD + bk8];

  for (int step = 0; step < 12; ++step) {
    int kb = step * 32;
    // write LDS from prefetch regs
#pragma unroll
    for (int p = 0; p < 4; ++p) {
      short4v b;
      b.x = (short)f2bf(pa[p].x); b.y = (short)f2bf(pa[p].y);
      b.z = (short)f2bf(pa[p].z); b.w = (short)f2bf(pa[p].w);
      *(short4v*)&sA[p * 32 + arow][akc] = b;
    }
#pragma unroll
    for (int p = 0; p < 2; ++p) *(int4*)&sB[p * 64 + bn][bk8] = pb[p];
    __syncthreads();
    if (step + 1 < 12) {
      int kn = kb + 32;
#pragma unroll
      for (int p = 0; p < 4; ++p) {
        int gr = rowbase + p * 32 + arow;
        pa[p] = (gr < NQ) ? *(const float4*)&qf[(size_t)gr * QD + kn + akc]
                          : make_float4(0.f, 0.f, 0.f, 0.f);
      }
#pragma unroll
      for (int p = 0; p < 2; ++p)
        pb[p] = *(const int4*)&Wqt[(size_t)(p * 64 + bn) * QD + kn + bk8];
    }
    short8 af[4], bfr[4];
#pragma unroll
    for (int mt = 0; mt < 4; ++mt)
      af[mt] = *(const short8*)&sA[wr + mt * 16 + l15][quad * 8];
#pragma unroll
    for (int nt = 0; nt < 4; ++nt)
      bfr[nt] = *(const short8*)&sB[wc + nt * 16 + l15][quad * 8];
#pragma unroll
    for (int mt = 0; mt < 4; ++mt)
#pragma unroll
      for (int nt = 0; nt < 4; ++nt)
        acc[mt][nt] = __builtin_amdgcn_mfma_f32_16x16x32_bf16(
            af[mt], bfr[nt], acc[mt][nt], 0, 0, 0);
    __syncthreads();
  }
#pragma unroll
  for (int nt = 0; nt < 4; ++nt) {
    int col = wc + nt * 16 + l15;
    float bias = bq[col];
#pragma unroll
    for (int mt = 0; mt < 4; ++mt) {
#pragma unroll
      for (int r = 0; r < 4; ++r) {
        int n = rowbase + wr + mt * 16 + quad * 4 + r;
        if (n < NQ) {
          float o = acc[mt][nt][r] + bias;
          XINI[(size_t)n * H + col] = o;
          XI16[(size_t)n * H + col] = f2bf(o);
        }
      }
    }
  }
}

// ---------------- segment sum (one wave per node), bf16 gather, S stored bf16 ----
// Gather reads the bf16 mirror (256B/row-wave instead of 512B): halves the
// biggest random-traffic stream in the pipeline (750K edges x row per layer).

template <bool TRANS>
__global__ __launch_bounds__(256) void k_seg(
    const unsigned short* __restrict__ Xin16, const int* __restrict__ off,
    const int* __restrict__ csr_src, const float* __restrict__ csr_ew,
    const float* __restrict__ scale, const float* __restrict__ shift,
    unsigned short* __restrict__ S16, float* __restrict__ swsum,
    float* __restrict__ degf) {
  int w = blockIdx.x * 4 + (threadIdx.x >> 6);
  if (w >= NN) return;
  int lane = threadIdx.x & 63;
  int o0 = off[w], o1 = off[w + 1];
  float ax = 1.f, ay = 1.f, bx = 0.f, by = 0.f;
  if (TRANS) {
    float2 sc = *(const float2*)&scale[lane * 2];
    float2 sh = *(const float2*)&shift[lane * 2];
    ax = sc.x; ay = sc.y; bx = sh.x; by = sh.y;
  }
  float accx = 0.f, accy = 0.f, ews = 0.f;
  for (int k = o0; k < o1; ++k) {
    int s = csr_src[k];
    unsigned int pv = *(const unsigned int*)&Xin16[(size_t)s * H + lane * 2];
    float vx = __builtin_bit_cast(float, pv << 16);
    float vy = __builtin_bit_cast(float, pv & 0xFFFF0000u);
    if (TRANS) {
      float t0 = fmaf(ax, vx, bx); vx = t0 > 0.f ? t0 : 0.01f * t0;
      float t1 = fmaf(ay, vy, by); vy = t1 > 0.f ? t1 : 0.01f * t1;
    }
    accx += vx; accy += vy;
    ews += csr_ew[k];
  }
  unsigned int pk = ((unsigned int)f2bf(accy) << 16) | f2bf(accx);
  *(unsigned int*)&S16[(size_t)w * H + lane * 2] = pk;
  if (lane == 0) { swsum[w] = ews; degf[w] = (float)(o1 - o0); }
}

// ---------------- node GEMM (bf16 MFMA) + residual + BN partials ----------------
// out = S@W + deg*(bm+be) + swsum*We + resid(in); resid: TRANS ? lrelu(a*in+b) : in
// X16out (nullable): bf16 mirror of the output for the next layer's gather.

template <bool TRANS>
__global__ __launch_bounds__(256) void k_gemm(
    const unsigned short* __restrict__ S16, const float* __restrict__ Xin,
    float* __restrict__ Xout, unsigned short* __restrict__ X16out,
    const unsigned short* __restrict__ Wt,
    const float* __restrict__ bm, const float* __restrict__ be,
    const float* __restrict__ We,
    const float* __restrict__ scale, const float* __restrict__ shift,
    const float* __restrict__ swsum, const float* __restrict__ degf,
    float* __restrict__ partials) {
  __shared__ unsigned short sA[128][40];
  __shared__ unsigned short sB[128][40];
  __shared__ float st[2][8][128];
  int tid = threadIdx.x;
  int w = tid >> 6, lane = tid & 63;
  int l15 = lane & 15, quad = lane >> 4;
  int wr = (w >> 1) * 64, wc = (w & 1) * 64;
  int rowbase = blockIdx.x * 128;
  f32x4 acc[4][4];
#pragma unroll
  for (int i = 0; i < 4; i++)
#pragma unroll
    for (int j = 0; j < 4; j++) acc[i][j] = (f32x4){0.f, 0.f, 0.f, 0.f};

  int arow = tid >> 1, ah = (tid & 1) * 16;  // 128 rows x 32 k per step
  int4 pa[2], pb[2];
  {
    int gr = rowbase + arow;
    if (gr < NN) {
      pa[0] = *(const int4*)&S16[(size_t)gr * H + ah];
      pa[1] = *(const int4*)&S16[(size_t)gr * H + ah + 8];
    } else {
      pa[0] = make_int4(0, 0, 0, 0); pa[1] = make_int4(0, 0, 0, 0);
    }
    pb[0] = *(const int4*)&Wt[(size_t)arow * H + ah];
    pb[1] = *(const int4*)&Wt[(size_t)arow * H + ah + 8];
  }
  for (int step = 0; step < 4; ++step) {
    *(int4*)&sA[arow][ah] = pa[0];
    *(int4*)&sA[arow][ah + 8] = pa[1];
    *(int4*)&sB[arow][ah] = pb[0];
    *(int4*)&sB[arow][ah + 8] = pb[1];
    __syncthreads();
    if (step + 1 < 4) {
      int kn = (step + 1) * 32;
      int gr = rowbase + arow;
      if (gr < NN) {
        pa[0] = *(const int4*)&S16[(size_t)gr * H + kn + ah];
        pa[1] = *(const int4*)&S16[(size_t)gr * H + kn + ah + 8];
      } else {
        pa[0] = make_int4(0, 0, 0, 0); pa[1] = make_int4(0, 0, 0, 0);
      }
      pb[0] = *(const int4*)&Wt[(size_t)arow * H + kn + ah];
      pb[1] = *(const int4*)&Wt[(size_t)arow * H + kn + ah + 8];
    }
    short8 af[4], bfr[4];
#pragma unroll
    for (int mt = 0; mt < 4; ++mt)
      af[mt] = *(const short8*)&sA[wr + mt * 16 + l15][quad * 8];
#pragma unroll
    for (int nt = 0; nt < 4; ++nt)
      bfr[nt] = *(const short8*)&sB[wc + nt * 16 + l15][quad * 8];
#pragma unroll
    for (int mt = 0; mt < 4; ++mt)
#pragma unroll
      for (int nt = 0; nt < 4; ++nt)
        acc[mt][nt] = __builtin_amdgcn_mfma_f32_16x16x32_bf16(
            af[mt], bfr[nt], acc[mt][nt], 0, 0, 0);
    __syncthreads();
  }
  // epilogue
  int col4[4];
  float cb4[4], we4[4], sc4[4], sh4[4], ps[4], pq[4];
#pragma unroll
  for (int nt = 0; nt < 4; ++nt) {
    int col = wc + nt * 16 + l15;
    col4[nt] = col;
    cb4[nt] = bm[col] + be[col];
    we4[nt] = We[col];
    if (TRANS) { sc4[nt] = scale[col]; sh4[nt] = shift[col]; }
    ps[nt] = 0.f; pq[nt] = 0.f;
  }
#pragma unroll
  for (int mt = 0; mt < 4; ++mt) {
#pragma unroll
    for (int r = 0; r < 4; ++r) {
      int n = rowbase + wr + mt * 16 + quad * 4 + r;
      if (n < NN) {
        float dg = degf[n], sw = swsum[n];
#pragma unroll
        for (int nt = 0; nt < 4; ++nt) {
          float rr = Xin[(size_t)n * H + col4[nt]];
          if (TRANS) {
            float t = fmaf(sc4[nt], rr, sh4[nt]);
            rr = t > 0.f ? t : 0.01f * t;
          }
          float o = acc[mt][nt][r] + dg * cb4[nt] + sw * we4[nt] + rr;
          Xout[(size_t)n * H + col4[nt]] = o;
          if (X16out) X16out[(size_t)n * H + col4[nt]] = f2bf(o);
          ps[nt] += o; pq[nt] += o * o;
        }
      }
    }
  }
  int slot = (w >> 1) * 4 + quad;
#pragma unroll
  for (int nt = 0; nt < 4; ++nt) {
    st[0][slot][col4[nt]] = ps[nt];
    st[1][slot][col4[nt]] = pq[nt];
  }
  __syncthreads();
  int plane = tid >> 7, col = tid & 127;
  float s = 0.f;
#pragma unroll
  for (int y = 0; y < 8; y++) s += st[plane][y][col];
  partials[(size_t)blockIdx.x * 256 + tid] = s;
}

// ---------------- BN stats finish: one block per column ----------------

__global__ __launch_bounds__(256) void k_bnstats(
    const float* __restrict__ partials, const float* __restrict__ g,
    const float* __restrict__ beta, float* __restrict__ scale,
    float* __restrict__ shift) {
  __shared__ float rs[256], rq[256];
  int j = blockIdx.x;  // column
  int t = threadIdx.x;
  float as = 0.f, aq = 0.f;
  for (int b = t; b < NB_GEMM; b += 256) {
    as += partials[(size_t)b * 256 + j];
    aq += partials[(size_t)b * 256 + 128 + j];
  }
  rs[t] = as; rq[t] = aq;
  __syncthreads();
  for (int s = 128; s > 0; s >>= 1) {
    if (t < s) { rs[t] += rs[t + s]; rq[t] += rq[t + s]; }
    __syncthreads();
  }
  if (t == 0) {
    float mean = rs[0] / (float)NN;
    float var = rq[0] / (float)NN - mean * mean;
    float a = g[j] * rsqrtf(var + EPS);
    scale[j] = a;
    shift[j] = beta[j] - mean * a;
  }
}

// ---------------- edge predict (one wave per edge) ----------------

__global__ __launch_bounds__(256) void k_pred(
    const int* __restrict__ emask, const int* __restrict__ EI,
    const float* __restrict__ XINI, const float* __restrict__ X,
    const float* __restrict__ scale, const float* __restrict__ shift,
    float* __restrict__ out) {
  int i = blockIdx.x * 4 + (threadIdx.x >> 6);
  if (i >= E_PRED) return;
  int lane = threadIdx.x & 63;
  int m = emask[i];
  int p0 = EI[m];
  int p1 = EI[E_TOT + m];
  float2 a = *(const float2*)&XINI[(size_t)p0 * H + lane * 2];
  float2 b = *(const float2*)&X[(size_t)p1 * H + lane * 2];
  float2 sc = *(const float2*)&scale[lane * 2];
  float2 sh = *(const float2*)&shift[lane * 2];
  float v = a.x * fmaf(sc.x, b.x, sh.x) + a.y * fmaf(sc.y, b.y, sh.y);
#pragma unroll
  for (int mm = 32; mm > 0; mm >>= 1) v += __shfl_xor(v, mm, 64);
  if (lane == 0) out[i] = 1.f / (1.f + expf(-v * (1.f / 128.f)));
}

// ---------------- launcher ----------------

extern "C" void kernel_launch(void* const* d_in, const int* in_sizes, int n_in,
                              void* d_out, int out_size, void* d_ws, size_t ws_size,
                              hipStream_t stream) {
  const float* qf    = (const float*)d_in[0];
  const float* lf    = (const float*)d_in[1];
  const int*   EI    = (const int*)d_in[2];
  const int*   emask = (const int*)d_in[3];
  const int*   ecs   = (const int*)d_in[4];
  const float* ewt   = (const float*)d_in[5];
  const float* Wq    = (const float*)d_in[6];
  const float* bq    = (const float*)d_in[7];
  const float* Wl    = (const float*)d_in[8];
  const float* bl    = (const float*)d_in[9];
  const float* Wem   = (const float*)d_in[10];
  const float* bem   = (const float*)d_in[11];
  const float* W1m   = (const float*)d_in[12];
  const float* b1m   = (const float*)d_in[13];
  const float* W1e   = (const float*)d_in[14];
  const float* b1e   = (const float*)d_in[15];
  const float* W2m   = (const float*)d_in[16];
  const float* b2m   = (const float*)d_in[17];
  const float* W2e   = (const float*)d_in[18];
  const float* b2e   = (const float*)d_in[19];
  const float* g1    = (const float*)d_in[20];
  const float* beta1 = (const float*)d_in[21];
  const float* g2    = (const float*)d_in[22];
  const float* beta2 = (const float*)d_in[23];
  float* out = (float*)d_out;

  char* p = (char*)d_ws;
  auto alloc = [&](size_t bytes) -> void* {
    void* r = (void*)p;
    p += (bytes + 255) & ~(size_t)255;
    return r;
  };
  float* XINI    = (float*)alloc((size_t)NN * H * 4);
  float* X       = (float*)alloc((size_t)NN * H * 4);
  unsigned short* XI16 = (unsigned short*)alloc((size_t)NN * H * 2);
  unsigned short* X16  = (unsigned short*)alloc((size_t)NN * H * 2);
  unsigned short* S16 = (unsigned short*)alloc((size_t)NN * H * 2);
  float* ew      = (float*)alloc((size_t)E_SEE * 4);
  float* csr_ew  = (float*)alloc((size_t)E_SEE * 4);
  int*   csr_src = (int*)alloc((size_t)E_SEE * 4);
  int*   cnt     = (int*)alloc((size_t)NN * 4);
  int*   off     = (int*)alloc((size_t)(NN + 1) * 4);
  int*   cur     = (int*)alloc((size_t)NN * 4);
  int*   bsum    = (int*)alloc((size_t)NB_SCAN * 4);
  int*   boff    = (int*)alloc((size_t)NB_SCAN * 4);
  float* swsum   = (float*)alloc((size_t)NN * 4);
  float* degf    = (float*)alloc((size_t)NN * 4);
  float* partials= (float*)alloc((size_t)NB_GEMM * 256 * 4);
  float* scale1  = (float*)alloc(128 * 4);
  float* shift1  = (float*)alloc(128 * 4);
  float* scale2  = (float*)alloc(128 * 4);
  float* shift2  = (float*)alloc(128 * 4);
  unsigned short* Wqt = (unsigned short*)alloc((size_t)QD * H * 2);
  unsigned short* W1t = (unsigned short*)alloc((size_t)H * H * 2);
  unsigned short* W2t = (unsigned short*)alloc((size_t)H * H * 2);
  float* llmpart = (float*)alloc((size_t)NL * 8 * H * 4);

  hipMemsetAsync(cnt, 0, (size_t)NN * 4, stream);
  hipMemsetAsync(cur, 0, (size_t)NN * 4, stream);

  int ebl = (E_SEE + 255) / 256;
  k_prep<<<320, 256, 0, stream>>>(Wq, W1m, W2m, Wqt, W1t, W2t);
  k_ew_hist<<<ebl, 256, 0, stream>>>(ecs, EI, ewt, Wem, bem, ew, cnt);
  k_scan_block<<<NB_SCAN, 256, 0, stream>>>(cnt, bsum);
  k_scan_top<<<1, 512, 0, stream>>>(bsum, boff);
  k_scan_write<<<NB_SCAN, 256, 0, stream>>>(cnt, boff, off);
  k_fill<<<ebl, 256, 0, stream>>>(ecs, EI, ew, off, cur, csr_src, csr_ew);

  k_llm_part<<<NL * 8, 128, 0, stream>>>(lf, Wl, llmpart);
  k_llm_comb<<<(NL * H + 255) / 256, 256, 0, stream>>>(llmpart, bl, XINI, XI16);
  k_xini<<<NB_XINI, 256, 0, stream>>>(qf, Wqt, bq, XINI, XI16);

  int segbl = (NN + 3) / 4;
  // layer 1 (gather reads bf16 mirror of x_ini)
  k_seg<false><<<segbl, 256, 0, stream>>>(XI16, off, csr_src, csr_ew,
                                          nullptr, nullptr, S16, swsum, degf);
  k_gemm<false><<<NB_GEMM, 256, 0, stream>>>(S16, XINI, X, X16, W1t, b1m, b1e, W1e,
                                             nullptr, nullptr, swsum, degf, partials);
  k_bnstats<<<H, 256, 0, stream>>>(partials, g1, beta1, scale1, shift1);
  // layer 2 (BN1+lrelu folded into gather & residual; gather reads bf16 X)
  k_seg<true><<<segbl, 256, 0, stream>>>(X16, off, csr_src, csr_ew,
                                         scale1, shift1, S16, swsum, degf);
  k_gemm<true><<<NB_GEMM, 256, 0, stream>>>(S16, X, X, nullptr, W2t, b2m, b2e, W2e,
                                            scale1, shift1, swsum, degf, partials);
  k_bnstats<<<H, 256, 0, stream>>>(partials, g2, beta2, scale2, shift2);
  // predict (BN2 folded in)
  int pbl = (E_PRED + 3) / 4;
  k_pred<<<pbl, 256, 0, stream>>>(emask, EI, XINI, X, scale2, shift2, out);
}

// Round 6
// 687.379 us; speedup vs baseline: 1.1418x; 1.1064x over previous
//
#include <hip/hip_runtime.h>
#include <math.h>

#define NQ 100000
#define NL 32
#define QD 384
#define LD 1024
#define H 128
#define E_TOT 1000000
#define E_SEE 750000
#define E_PRED 250000
#define NN (NQ + NL)          // 100032
#define EPS 1e-5f

#define NB_SCAN ((NN + 255) / 256)    // 391
#define NB_GEMM ((NN + 127) / 128)    // 782
#define NB_XINI ((NQ + 127) / 128)    // 782

typedef __attribute__((ext_vector_type(8))) short short8;
typedef __attribute__((ext_vector_type(4))) short short4v;
typedef __attribute__((ext_vector_type(4))) float f32x4;

__device__ __forceinline__ unsigned short f2bf(float f) {
  unsigned int u = __builtin_bit_cast(unsigned int, f);
  u = (u + 0x7FFFu + ((u >> 16) & 1u)) >> 16;
  return (unsigned short)u;
}

// ---------------- CSR build ----------------

__global__ void k_ew_hist(const int* __restrict__ ecs, const int* __restrict__ EI,
                          const float* __restrict__ ewt, const float* __restrict__ Wem,
                          const float* __restrict__ bem, float* __restrict__ ew,
                          int* __restrict__ cnt) {
  int e = blockIdx.x * 256 + threadIdx.x;
  if (e >= E_SEE) return;
  int idx = ecs[e];
  int d = EI[E_TOT + idx];
  atomicAdd(&cnt[d], 1);
  float w = ewt[idx] * Wem[0] + bem[0];
  ew[e] = w > 0.f ? w : 0.01f * w;
}

__global__ void k_scan_block(const int* __restrict__ cnt, int* __restrict__ bsum) {
  __shared__ int red[256];
  int i = blockIdx.x * 256 + threadIdx.x;
  red[threadIdx.x] = (i < NN) ? cnt[i] : 0;
  __syncthreads();
  for (int s = 128; s > 0; s >>= 1) {
    if (threadIdx.x < s) red[threadIdx.x] += red[threadIdx.x + s];
    __syncthreads();
  }
  if (threadIdx.x == 0) bsum[blockIdx.x] = red[0];
}

__global__ void k_scan_top(const int* __restrict__ bsum, int* __restrict__ boff) {
  __shared__ int buf[2][512];
  int t = threadIdx.x;
  int v = (t < NB_SCAN) ? bsum[t] : 0;
  buf[0][t] = v;
  __syncthreads();
  int src = 0;
  for (int d = 1; d < 512; d <<= 1) {
    int x = buf[src][t];
    if (t >= d) x += buf[src][t - d];
    buf[src ^ 1][t] = x;
    __syncthreads();
    src ^= 1;
  }
  if (t < NB_SCAN) boff[t] = buf[src][t] - v;  // exclusive
}

__global__ void k_scan_write(const int* __restrict__ cnt, const int* __restrict__ boff,
                             int* __restrict__ off) {
  __shared__ int buf[2][256];
  int t = threadIdx.x;
  int i = blockIdx.x * 256 + t;
  int v = (i < NN) ? cnt[i] : 0;
  buf[0][t] = v;
  __syncthreads();
  int src = 0;
  for (int d = 1; d < 256; d <<= 1) {
    int x = buf[src][t];
    if (t >= d) x += buf[src][t - d];
    buf[src ^ 1][t] = x;
    __syncthreads();
    src ^= 1;
  }
  if (i < NN) off[i] = boff[blockIdx.x] + buf[src][t] - v;
  if (i == 0) off[NN] = E_SEE;
}

__global__ void k_fill(const int* __restrict__ ecs, const int* __restrict__ EI,
                       const float* __restrict__ ew, const int* __restrict__ off,
                       int* __restrict__ cur, int* __restrict__ csr_src,
                       float* __restrict__ csr_ew) {
  int e = blockIdx.x * 256 + threadIdx.x;
  if (e >= E_SEE) return;
  int idx = ecs[e];
  int s = EI[idx];
  int d = EI[E_TOT + idx];
  int p = off[d] + atomicAdd(&cur[d], 1);
  csr_src[p] = s;
  csr_ew[p] = ew[e];
}

// ---------------- prep: bf16 transposed weights [n][k] ----------------

__global__ void k_prep(const float* __restrict__ Wq, const float* __restrict__ W1m,
                       const float* __restrict__ W2m,
                       unsigned short* __restrict__ Wqt, unsigned short* __restrict__ W1t,
                       unsigned short* __restrict__ W2t) {
  int i = blockIdx.x * 256 + threadIdx.x;  // grid covers 81920
  const int tot1 = QD * H;                 // 49152
  const int tot2 = H * H;                  // 16384
  if (i < tot1) {
    int n = i / QD, k = i - n * QD;
    Wqt[i] = f2bf(Wq[(size_t)k * H + n]);
  } else if (i < tot1 + tot2) {
    int j = i - tot1;
    int n = j >> 7, k = j & 127;
    W1t[j] = f2bf(W1m[(size_t)k * H + n]);
  } else if (i < tot1 + 2 * tot2) {
    int j = i - tot1 - tot2;
    int n = j >> 7, k = j & 127;
    W2t[j] = f2bf(W2m[(size_t)k * H + n]);
  }
}

// ---------------- llm rows: split-K partial + combine ----------------

__global__ __launch_bounds__(128) void k_llm_part(const float* __restrict__ lf,
                                                  const float* __restrict__ Wl,
                                                  float* __restrict__ part) {
  int r = blockIdx.x >> 3;   // 0..31
  int s = blockIdx.x & 7;    // 0..7
  int t = threadIdx.x;       // col 0..127
  int k0 = s * 128;
  float acc = 0.f;
#pragma unroll 4
  for (int k = 0; k < 128; k += 4) {
    float a0 = lf[(size_t)r * LD + k0 + k + 0];
    float a1 = lf[(size_t)r * LD + k0 + k + 1];
    float a2 = lf[(size_t)r * LD + k0 + k + 2];
    float a3 = lf[(size_t)r * LD + k0 + k + 3];
    acc = fmaf(a0, Wl[(size_t)(k0 + k + 0) * H + t], acc);
    acc = fmaf(a1, Wl[(size_t)(k0 + k + 1) * H + t], acc);
    acc = fmaf(a2, Wl[(size_t)(k0 + k + 2) * H + t], acc);
    acc = fmaf(a3, Wl[(size_t)(k0 + k + 3) * H + t], acc);
  }
  part[(size_t)blockIdx.x * 128 + t] = acc;
}

__global__ void k_llm_comb(const float* __restrict__ part, const float* __restrict__ bl,
                           float* __restrict__ XINI, unsigned short* __restrict__ XI16) {
  int i = blockIdx.x * 256 + threadIdx.x;
  if (i >= NL * H) return;
  int r = i >> 7, t = i & 127;
  float a = bl[t];
#pragma unroll
  for (int s = 0; s < 8; s++) a += part[(size_t)(r * 8 + s) * 128 + t];
  XINI[(size_t)(NQ + r) * H + t] = a;
  XI16[(size_t)(NQ + r) * H + t] = f2bf(a);
}

// ---------------- x_ini q rows: bf16 MFMA 128x128 tile, K=384 ----------------
// (round-0 proven structure: LDS A+B, 107 us; do not re-roll — r1-r4 all lost)

__global__ __launch_bounds__(256) void k_xini(
    const float* __restrict__ qf, const unsigned short* __restrict__ Wqt,
    const float* __restrict__ bq, float* __restrict__ XINI,
    unsigned short* __restrict__ XI16) {
  __shared__ unsigned short sA[128][40];  // pad: 20-dword stride
  __shared__ unsigned short sB[128][40];
  int tid = threadIdx.x;
  int w = tid >> 6, lane = tid & 63;
  int l15 = lane & 15, quad = lane >> 4;
  int wr = (w >> 1) * 64, wc = (w & 1) * 64;
  int rowbase = blockIdx.x * 128;
  f32x4 acc[4][4];
#pragma unroll
  for (int i = 0; i < 4; i++)
#pragma unroll
    for (int j = 0; j < 4; j++) acc[i][j] = (f32x4){0.f, 0.f, 0.f, 0.f};

  int arow = tid >> 3, akc = (tid & 7) * 4;
  int bn = tid >> 2, bk8 = (tid & 3) * 8;
  float4 pa[4];
  int4 pb[2];
  // preload step 0
#pragma unroll
  for (int p = 0; p < 4; ++p) {
    int gr = rowbase + p * 32 + arow;
    pa[p] = (gr < NQ) ? *(const float4*)&qf[(size_t)gr * QD + akc]
                      : make_float4(0.f, 0.f, 0.f, 0.f);
  }
#pragma unroll
  for (int p = 0; p < 2; ++p)
    pb[p] = *(const int4*)&Wqt[(size_t)(p * 64 + bn) * QD + bk8];

  for (int step = 0; step < 12; ++step) {
    int kb = step * 32;
    // write LDS from prefetch regs
#pragma unroll
    for (int p = 0; p < 4; ++p) {
      short4v b;
      b.x = (short)f2bf(pa[p].x); b.y = (short)f2bf(pa[p].y);
      b.z = (short)f2bf(pa[p].z); b.w = (short)f2bf(pa[p].w);
      *(short4v*)&sA[p * 32 + arow][akc] = b;
    }
#pragma unroll
    for (int p = 0; p < 2; ++p) *(int4*)&sB[p * 64 + bn][bk8] = pb[p];
    __syncthreads();
    if (step + 1 < 12) {
      int kn = kb + 32;
#pragma unroll
      for (int p = 0; p < 4; ++p) {
        int gr = rowbase + p * 32 + arow;
        pa[p] = (gr < NQ) ? *(const float4*)&qf[(size_t)gr * QD + kn + akc]
                          : make_float4(0.f, 0.f, 0.f, 0.f);
      }
#pragma unroll
      for (int p = 0; p < 2; ++p)
        pb[p] = *(const int4*)&Wqt[(size_t)(p * 64 + bn) * QD + kn + bk8];
    }
    short8 af[4], bfr[4];
#pragma unroll
    for (int mt = 0; mt < 4; ++mt)
      af[mt] = *(const short8*)&sA[wr + mt * 16 + l15][quad * 8];
#pragma unroll
    for (int nt = 0; nt < 4; ++nt)
      bfr[nt] = *(const short8*)&sB[wc + nt * 16 + l15][quad * 8];
#pragma unroll
    for (int mt = 0; mt < 4; ++mt)
#pragma unroll
      for (int nt = 0; nt < 4; ++nt)
        acc[mt][nt] = __builtin_amdgcn_mfma_f32_16x16x32_bf16(
            af[mt], bfr[nt], acc[mt][nt], 0, 0, 0);
    __syncthreads();
  }
#pragma unroll
  for (int nt = 0; nt < 4; ++nt) {
    int col = wc + nt * 16 + l15;
    float bias = bq[col];
#pragma unroll
    for (int mt = 0; mt < 4; ++mt) {
#pragma unroll
      for (int r = 0; r < 4; ++r) {
        int n = rowbase + wr + mt * 16 + quad * 4 + r;
        if (n < NQ) {
          float o = acc[mt][nt][r] + bias;
          XINI[(size_t)n * H + col] = o;
          XI16[(size_t)n * H + col] = f2bf(o);
        }
      }
    }
  }
}

// ---------------- segment sum (one wave per node), bf16 gather, S stored bf16 ----
// 4-edge MLP unroll with clamped-index tail masking: the gather was measured
// latency-bound (r5: halving gather bytes changed nothing), so the lever is
// memory-level parallelism — 4 independent row loads in flight per iteration
// instead of a serial idx->row dependent chain per edge. Every iteration is
// 4-wide (tail edges clamp to the last valid index; contributions masked).

template <bool TRANS>
__global__ __launch_bounds__(256) void k_seg(
    const unsigned short* __restrict__ Xin16, const int* __restrict__ off,
    const int* __restrict__ csr_src, const float* __restrict__ csr_ew,
    const float* __restrict__ scale, const float* __restrict__ shift,
    unsigned short* __restrict__ S16, float* __restrict__ swsum,
    float* __restrict__ degf) {
  int w = blockIdx.x * 4 + (threadIdx.x >> 6);
  if (w >= NN) return;
  int lane = threadIdx.x & 63;
  int o0 = off[w], o1 = off[w + 1];
  float ax = 1.f, ay = 1.f, bx = 0.f, by = 0.f;
  if (TRANS) {
    float2 sc = *(const float2*)&scale[lane * 2];
    float2 sh = *(const float2*)&shift[lane * 2];
    ax = sc.x; ay = sc.y; bx = sh.x; by = sh.y;
  }
  const unsigned short* xb = Xin16 + lane * 2;
  float accx = 0.f, accy = 0.f, ews = 0.f;
  int e1 = o1 - 1;
  for (int k = o0; k < o1; k += 4) {
    int k1 = k + 1 <= e1 ? k + 1 : e1;
    int k2 = k + 2 <= e1 ? k + 2 : e1;
    int k3 = k + 3 <= e1 ? k + 3 : e1;
    bool m1 = k + 1 < o1, m2 = k + 2 < o1, m3 = k + 3 < o1;
    // 4 sequential index/weight loads issue together...
    int s0 = csr_src[k],  s1 = csr_src[k1];
    int s2 = csr_src[k2], s3 = csr_src[k3];
    float w0 = csr_ew[k],  w1 = csr_ew[k1];
    float w2 = csr_ew[k2], w3 = csr_ew[k3];
    // ...then 4 independent row loads in flight (the MLP win)
    unsigned int p0 = *(const unsigned int*)&xb[(size_t)s0 * H];
    unsigned int p1 = *(const unsigned int*)&xb[(size_t)s1 * H];
    unsigned int p2 = *(const unsigned int*)&xb[(size_t)s2 * H];
    unsigned int p3 = *(const unsigned int*)&xb[(size_t)s3 * H];
    if (!m1) w1 = 0.f;
    if (!m2) w2 = 0.f;
    if (!m3) w3 = 0.f;
    ews += (w0 + w1) + (w2 + w3);
    {
      float vx = __builtin_bit_cast(float, p0 << 16);
      float vy = __builtin_bit_cast(float, p0 & 0xFFFF0000u);
      if (TRANS) {
        float t0 = fmaf(ax, vx, bx); vx = t0 > 0.f ? t0 : 0.01f * t0;
        float t1 = fmaf(ay, vy, by); vy = t1 > 0.f ? t1 : 0.01f * t1;
      }
      accx += vx; accy += vy;
    }
    {
      float vx = __builtin_bit_cast(float, p1 << 16);
      float vy = __builtin_bit_cast(float, p1 & 0xFFFF0000u);
      if (TRANS) {
        float t0 = fmaf(ax, vx, bx); vx = t0 > 0.f ? t0 : 0.01f * t0;
        float t1 = fmaf(ay, vy, by); vy = t1 > 0.f ? t1 : 0.01f * t1;
      }
      accx += m1 ? vx : 0.f; accy += m1 ? vy : 0.f;
    }
    {
      float vx = __builtin_bit_cast(float, p2 << 16);
      float vy = __builtin_bit_cast(float, p2 & 0xFFFF0000u);
      if (TRANS) {
        float t0 = fmaf(ax, vx, bx); vx = t0 > 0.f ? t0 : 0.01f * t0;
        float t1 = fmaf(ay, vy, by); vy = t1 > 0.f ? t1 : 0.01f * t1;
      }
      accx += m2 ? vx : 0.f; accy += m2 ? vy : 0.f;
    }
    {
      float vx = __builtin_bit_cast(float, p3 << 16);
      float vy = __builtin_bit_cast(float, p3 & 0xFFFF0000u);
      if (TRANS) {
        float t0 = fmaf(ax, vx, bx); vx = t0 > 0.f ? t0 : 0.01f * t0;
        float t1 = fmaf(ay, vy, by); vy = t1 > 0.f ? t1 : 0.01f * t1;
      }
      accx += m3 ? vx : 0.f; accy += m3 ? vy : 0.f;
    }
  }
  unsigned int pk = ((unsigned int)f2bf(accy) << 16) | f2bf(accx);
  *(unsigned int*)&S16[(size_t)w * H + lane * 2] = pk;
  if (lane == 0) { swsum[w] = ews; degf[w] = (float)(o1 - o0); }
}

// ---------------- node GEMM (bf16 MFMA) + residual + BN partials ----------------
// out = S@W + deg*(bm+be) + swsum*We + resid(in); resid: TRANS ? lrelu(a*in+b) : in
// X16out (nullable): bf16 mirror of the output for the next layer's gather.

template <bool TRANS>
__global__ __launch_bounds__(256) void k_gemm(
    const unsigned short* __restrict__ S16, const float* __restrict__ Xin,
    float* __restrict__ Xout, unsigned short* __restrict__ X16out,
    const unsigned short* __restrict__ Wt,
    const float* __restrict__ bm, const float* __restrict__ be,
    const float* __restrict__ We,
    const float* __restrict__ scale, const float* __restrict__ shift,
    const float* __restrict__ swsum, const float* __restrict__ degf,
    float* __restrict__ partials) {
  __shared__ unsigned short sA[128][40];
  __shared__ unsigned short sB[128][40];
  __shared__ float st[2][8][128];
  int tid = threadIdx.x;
  int w = tid >> 6, lane = tid & 63;
  int l15 = lane & 15, quad = lane >> 4;
  int wr = (w >> 1) * 64, wc = (w & 1) * 64;
  int rowbase = blockIdx.x * 128;
  f32x4 acc[4][4];
#pragma unroll
  for (int i = 0; i < 4; i++)
#pragma unroll
    for (int j = 0; j < 4; j++) acc[i][j] = (f32x4){0.f, 0.f, 0.f, 0.f};

  int arow = tid >> 1, ah = (tid & 1) * 16;  // 128 rows x 32 k per step
  int4 pa[2], pb[2];
  {
    int gr = rowbase + arow;
    if (gr < NN) {
      pa[0] = *(const int4*)&S16[(size_t)gr * H + ah];
      pa[1] = *(const int4*)&S16[(size_t)gr * H + ah + 8];
    } else {
      pa[0] = make_int4(0, 0, 0, 0); pa[1] = make_int4(0, 0, 0, 0);
    }
    pb[0] = *(const int4*)&Wt[(size_t)arow * H + ah];
    pb[1] = *(const int4*)&Wt[(size_t)arow * H + ah + 8];
  }
  for (int step = 0; step < 4; ++step) {
    *(int4*)&sA[arow][ah] = pa[0];
    *(int4*)&sA[arow][ah + 8] = pa[1];
    *(int4*)&sB[arow][ah] = pb[0];
    *(int4*)&sB[arow][ah + 8] = pb[1];
    __syncthreads();
    if (step + 1 < 4) {
      int kn = (step + 1) * 32;
      int gr = rowbase + arow;
      if (gr < NN) {
        pa[0] = *(const int4*)&S16[(size_t)gr * H + kn + ah];
        pa[1] = *(const int4*)&S16[(size_t)gr * H + kn + ah + 8];
      } else {
        pa[0] = make_int4(0, 0, 0, 0); pa[1] = make_int4(0, 0, 0, 0);
      }
      pb[0] = *(const int4*)&Wt[(size_t)arow * H + kn + ah];
      pb[1] = *(const int4*)&Wt[(size_t)arow * H + kn + ah + 8];
    }
    short8 af[4], bfr[4];
#pragma unroll
    for (int mt = 0; mt < 4; ++mt)
      af[mt] = *(const short8*)&sA[wr + mt * 16 + l15][quad * 8];
#pragma unroll
    for (int nt = 0; nt < 4; ++nt)
      bfr[nt] = *(const short8*)&sB[wc + nt * 16 + l15][quad * 8];
#pragma unroll
    for (int mt = 0; mt < 4; ++mt)
#pragma unroll
      for (int nt = 0; nt < 4; ++nt)
        acc[mt][nt] = __builtin_amdgcn_mfma_f32_16x16x32_bf16(
            af[mt], bfr[nt], acc[mt][nt], 0, 0, 0);
    __syncthreads();
  }
  // epilogue
  int col4[4];
  float cb4[4], we4[4], sc4[4], sh4[4], ps[4], pq[4];
#pragma unroll
  for (int nt = 0; nt < 4; ++nt) {
    int col = wc + nt * 16 + l15;
    col4[nt] = col;
    cb4[nt] = bm[col] + be[col];
    we4[nt] = We[col];
    if (TRANS) { sc4[nt] = scale[col]; sh4[nt] = shift[col]; }
    ps[nt] = 0.f; pq[nt] = 0.f;
  }
#pragma unroll
  for (int mt = 0; mt < 4; ++mt) {
#pragma unroll
    for (int r = 0; r < 4; ++r) {
      int n = rowbase + wr + mt * 16 + quad * 4 + r;
      if (n < NN) {
        float dg = degf[n], sw = swsum[n];
#pragma unroll
        for (int nt = 0; nt < 4; ++nt) {
          float rr = Xin[(size_t)n * H + col4[nt]];
          if (TRANS) {
            float t = fmaf(sc4[nt], rr, sh4[nt]);
            rr = t > 0.f ? t : 0.01f * t;
          }
          float o = acc[mt][nt][r] + dg * cb4[nt] + sw * we4[nt] + rr;
          Xout[(size_t)n * H + col4[nt]] = o;
          if (X16out) X16out[(size_t)n * H + col4[nt]] = f2bf(o);
          ps[nt] += o; pq[nt] += o * o;
        }
      }
    }
  }
  int slot = (w >> 1) * 4 + quad;
#pragma unroll
  for (int nt = 0; nt < 4; ++nt) {
    st[0][slot][col4[nt]] = ps[nt];
    st[1][slot][col4[nt]] = pq[nt];
  }
  __syncthreads();
  int plane = tid >> 7, col = tid & 127;
  float s = 0.f;
#pragma unroll
  for (int y = 0; y < 8; y++) s += st[plane][y][col];
  partials[(size_t)blockIdx.x * 256 + tid] = s;
}

// ---------------- BN stats finish: one block per column ----------------

__global__ __launch_bounds__(256) void k_bnstats(
    const float* __restrict__ partials, const float* __restrict__ g,
    const float* __restrict__ beta, float* __restrict__ scale,
    float* __restrict__ shift) {
  __shared__ float rs[256], rq[256];
  int j = blockIdx.x;  // column
  int t = threadIdx.x;
  float as = 0.f, aq = 0.f;
  for (int b = t; b < NB_GEMM; b += 256) {
    as += partials[(size_t)b * 256 + j];
    aq += partials[(size_t)b * 256 + 128 + j];
  }
  rs[t] = as; rq[t] = aq;
  __syncthreads();
  for (int s = 128; s > 0; s >>= 1) {
    if (t < s) { rs[t] += rs[t + s]; rq[t] += rq[t + s]; }
    __syncthreads();
  }
  if (t == 0) {
    float mean = rs[0] / (float)NN;
    float var = rq[0] / (float)NN - mean * mean;
    float a = g[j] * rsqrtf(var + EPS);
    scale[j] = a;
    shift[j] = beta[j] - mean * a;
  }
}

// ---------------- edge predict (one wave per edge) ----------------

__global__ __launch_bounds__(256) void k_pred(
    const int* __restrict__ emask, const int* __restrict__ EI,
    const float* __restrict__ XINI, const float* __restrict__ X,
    const float* __restrict__ scale, const float* __restrict__ shift,
    float* __restrict__ out) {
  int i = blockIdx.x * 4 + (threadIdx.x >> 6);
  if (i >= E_PRED) return;
  int lane = threadIdx.x & 63;
  int m = emask[i];
  int p0 = EI[m];
  int p1 = EI[E_TOT + m];
  float2 a = *(const float2*)&XINI[(size_t)p0 * H + lane * 2];
  float2 b = *(const float2*)&X[(size_t)p1 * H + lane * 2];
  float2 sc = *(const float2*)&scale[lane * 2];
  float2 sh = *(const float2*)&shift[lane * 2];
  float v = a.x * fmaf(sc.x, b.x, sh.x) + a.y * fmaf(sc.y, b.y, sh.y);
#pragma unroll
  for (int mm = 32; mm > 0; mm >>= 1) v += __shfl_xor(v, mm, 64);
  if (lane == 0) out[i] = 1.f / (1.f + expf(-v * (1.f / 128.f)));
}

// ---------------- launcher ----------------

extern "C" void kernel_launch(void* const* d_in, const int* in_sizes, int n_in,
                              void* d_out, int out_size, void* d_ws, size_t ws_size,
                              hipStream_t stream) {
  const float* qf    = (const float*)d_in[0];
  const float* lf    = (const float*)d_in[1];
  const int*   EI    = (const int*)d_in[2];
  const int*   emask = (const int*)d_in[3];
  const int*   ecs   = (const int*)d_in[4];
  const float* ewt   = (const float*)d_in[5];
  const float* Wq    = (const float*)d_in[6];
  const float* bq    = (const float*)d_in[7];
  const float* Wl    = (const float*)d_in[8];
  const float* bl    = (const float*)d_in[9];
  const float* Wem   = (const float*)d_in[10];
  const float* bem   = (const float*)d_in[11];
  const float* W1m   = (const float*)d_in[12];
  const float* b1m   = (const float*)d_in[13];
  const float* W1e   = (const float*)d_in[14];
  const float* b1e   = (const float*)d_in[15];
  const float* W2m   = (const float*)d_in[16];
  const float* b2m   = (const float*)d_in[17];
  const float* W2e   = (const float*)d_in[18];
  const float* b2e   = (const float*)d_in[19];
  const float* g1    = (const float*)d_in[20];
  const float* beta1 = (const float*)d_in[21];
  const float* g2    = (const float*)d_in[22];
  const float* beta2 = (const float*)d_in[23];
  float* out = (float*)d_out;

  char* p = (char*)d_ws;
  auto alloc = [&](size_t bytes) -> void* {
    void* r = (void*)p;
    p += (bytes + 255) & ~(size_t)255;
    return r;
  };
  float* XINI    = (float*)alloc((size_t)NN * H * 4);
  float* X       = (float*)alloc((size_t)NN * H * 4);
  unsigned short* XI16 = (unsigned short*)alloc((size_t)NN * H * 2);
  unsigned short* X16  = (unsigned short*)alloc((size_t)NN * H * 2);
  unsigned short* S16 = (unsigned short*)alloc((size_t)NN * H * 2);
  float* ew      = (float*)alloc((size_t)E_SEE * 4);
  float* csr_ew  = (float*)alloc((size_t)E_SEE * 4);
  int*   csr_src = (int*)alloc((size_t)E_SEE * 4);
  int*   cnt     = (int*)alloc((size_t)NN * 4);
  int*   off     = (int*)alloc((size_t)(NN + 1) * 4);
  int*   cur     = (int*)alloc((size_t)NN * 4);
  int*   bsum    = (int*)alloc((size_t)NB_SCAN * 4);
  int*   boff    = (int*)alloc((size_t)NB_SCAN * 4);
  float* swsum   = (float*)alloc((size_t)NN * 4);
  float* degf    = (float*)alloc((size_t)NN * 4);
  float* partials= (float*)alloc((size_t)NB_GEMM * 256 * 4);
  float* scale1  = (float*)alloc(128 * 4);
  float* shift1  = (float*)alloc(128 * 4);
  float* scale2  = (float*)alloc(128 * 4);
  float* shift2  = (float*)alloc(128 * 4);
  unsigned short* Wqt = (unsigned short*)alloc((size_t)QD * H * 2);
  unsigned short* W1t = (unsigned short*)alloc((size_t)H * H * 2);
  unsigned short* W2t = (unsigned short*)alloc((size_t)H * H * 2);
  float* llmpart = (float*)alloc((size_t)NL * 8 * H * 4);

  hipMemsetAsync(cnt, 0, (size_t)NN * 4, stream);
  hipMemsetAsync(cur, 0, (size_t)NN * 4, stream);

  int ebl = (E_SEE + 255) / 256;
  k_prep<<<320, 256, 0, stream>>>(Wq, W1m, W2m, Wqt, W1t, W2t);
  k_ew_hist<<<ebl, 256, 0, stream>>>(ecs, EI, ewt, Wem, bem, ew, cnt);
  k_scan_block<<<NB_SCAN, 256, 0, stream>>>(cnt, bsum);
  k_scan_top<<<1, 512, 0, stream>>>(bsum, boff);
  k_scan_write<<<NB_SCAN, 256, 0, stream>>>(cnt, boff, off);
  k_fill<<<ebl, 256, 0, stream>>>(ecs, EI, ew, off, cur, csr_src, csr_ew);

  k_llm_part<<<NL * 8, 128, 0, stream>>>(lf, Wl, llmpart);
  k_llm_comb<<<(NL * H + 255) / 256, 256, 0, stream>>>(llmpart, bl, XINI, XI16);
  k_xini<<<NB_XINI, 256, 0, stream>>>(qf, Wqt, bq, XINI, XI16);

  int segbl = (NN + 3) / 4;
  // layer 1 (gather reads bf16 mirror of x_ini)
  k_seg<false><<<segbl, 256, 0, stream>>>(XI16, off, csr_src, csr_ew,
                                          nullptr, nullptr, S16, swsum, degf);
  k_gemm<false><<<NB_GEMM, 256, 0, stream>>>(S16, XINI, X, X16, W1t, b1m, b1e, W1e,
                                             nullptr, nullptr, swsum, degf, partials);
  k_bnstats<<<H, 256, 0, stream>>>(partials, g1, beta1, scale1, shift1);
  // layer 2 (BN1+lrelu folded into gather & residual; gather reads bf16 X)
  k_seg<true><<<segbl, 256, 0, stream>>>(X16, off, csr_src, csr_ew,
                                         scale1, shift1, S16, swsum, degf);
  k_gemm<true><<<NB_GEMM, 256, 0, stream>>>(S16, X, X, nullptr, W2t, b2m, b2e, W2e,
                                            scale1, shift1, swsum, degf, partials);
  k_bnstats<<<H, 256, 0, stream>>>(partials, g2, beta2, scale2, shift2);
  // predict (BN2 folded in)
  int pbl = (E_PRED + 3) / 4;
  k_pred<<<pbl, 256, 0, stream>>>(emask, EI, XINI, X, scale2, shift2, out);
}